// Round 1
// baseline (207.080 us; speedup 1.0000x reference)
//
#include <hip/hip_runtime.h>
#include <hip/hip_bf16.h>

#define LOG2E 1.4426950408889634f

typedef __attribute__((ext_vector_type(8))) short short8;
typedef __attribute__((ext_vector_type(8))) __bf16 bf16x8;
typedef __attribute__((ext_vector_type(4))) float f32x4;

__device__ __forceinline__ unsigned short f2b(float f){
  unsigned int u = __builtin_bit_cast(unsigned int, f);
  u += 0x7fffu + ((u >> 16) & 1u);
  return (unsigned short)(u >> 16);
}

// ---------------- conversion kernels ----------------
__global__ __launch_bounds__(256) void cvt_x_kernel(const float* __restrict__ in,
                                                    unsigned short* __restrict__ out){
  size_t i = ((size_t)blockIdx.x * 256 + threadIdx.x) * 8;
  float4 a = *(const float4*)(in + i);
  float4 b = *(const float4*)(in + i + 4);
  short8 s;
  s[0]=(short)f2b(a.x); s[1]=(short)f2b(a.y); s[2]=(short)f2b(a.z); s[3]=(short)f2b(a.w);
  s[4]=(short)f2b(b.x); s[5]=(short)f2b(b.y); s[6]=(short)f2b(b.z); s[7]=(short)f2b(b.w);
  *(short8*)(out + i) = s;
}

// out[c][r] = in[r][c]  (build B^T bf16)
__global__ __launch_bounds__(256) void cvt_tr_kernel(const float* __restrict__ in,
                                                     unsigned short* __restrict__ out,
                                                     int R, int C){
  int c = blockIdx.x * 256 + threadIdx.x;
  int r = blockIdx.y;
  if (c < C) out[(size_t)c * R + r] = f2b(in[(size_t)r * C + c]);
}

// ---------------- QKV GEMM ----------------
// A: xb [8192][512] bf16.  Bt: WqkvT [1536][512] bf16.  bias: bqkv [1536] f32.
// Output scattered to Q/K/V [B=4][H=8][T=2048][64] bf16; Q pre-scaled by 0.125.
__global__ __launch_bounds__(256,2) void gemm_qkv_kernel(
    const unsigned short* __restrict__ A,
    const unsigned short* __restrict__ Bt,
    const float* __restrict__ bias,
    unsigned short* __restrict__ Qb,
    unsigned short* __restrict__ Kb,
    unsigned short* __restrict__ Vb){
  __shared__ unsigned short As[128][40];
  __shared__ unsigned short Bs[128][40];
  const int tid = threadIdx.x, wid = tid >> 6, lane = tid & 63;
  const int wr = wid >> 1, wc = wid & 1;
  const int fr = lane & 15, fq = lane >> 4;
  const int bm = blockIdx.x * 128, bn = blockIdx.y * 128;
  const int srow = tid >> 2, scol = (tid & 3) * 8;
  f32x4 acc[4][4];
  #pragma unroll
  for (int m=0;m<4;m++)
    #pragma unroll
    for (int n=0;n<4;n++) acc[m][n] = (f32x4){0.f,0.f,0.f,0.f};

  for (int k0 = 0; k0 < 512; k0 += 32){
    __syncthreads();
    #pragma unroll
    for (int i=0;i<2;i++){
      int r = i*64 + srow;
      *(short8*)&As[r][scol] = *(const short8*)(A  + (size_t)(bm + r)*512 + k0 + scol);
      *(short8*)&Bs[r][scol] = *(const short8*)(Bt + (size_t)(bn + r)*512 + k0 + scol);
    }
    __syncthreads();
    bf16x8 af[4], bfv[4];
    #pragma unroll
    for (int m=0;m<4;m++) af[m]  = *(const bf16x8*)&As[wr*64 + m*16 + fr][fq*8];
    #pragma unroll
    for (int n=0;n<4;n++) bfv[n] = *(const bf16x8*)&Bs[wc*64 + n*16 + fr][fq*8];
    #pragma unroll
    for (int m=0;m<4;m++)
      #pragma unroll
      for (int n=0;n<4;n++)
        acc[m][n] = __builtin_amdgcn_mfma_f32_16x16x32_bf16(af[m], bfv[n], acc[m][n], 0,0,0);
  }

  #pragma unroll
  for (int m=0;m<4;m++){
    const int row0 = bm + wr*64 + m*16 + fq*4;
    #pragma unroll
    for (int n=0;n<4;n++){
      const int col = bn + wc*64 + n*16 + fr;
      const int which = col >> 9, c = col & 511, hh = c >> 6, dd = c & 63;
      const float bv = bias[col];
      unsigned short* dst = which==0 ? Qb : (which==1 ? Kb : Vb);
      const float sc = which==0 ? 0.125f : 1.0f;
      #pragma unroll
      for (int g=0; g<4; g++){
        const int rr = row0 + g;
        const int b_ = rr >> 11, t_ = rr & 2047;
        dst[((size_t)(b_*8 + hh)*2048 + t_)*64 + dd] = f2b((acc[m][n][g] + bv)*sc);
      }
    }
  }
}

// ---------------- flash attention ----------------
// Q/K/V: [32 (b*8+h)][2048][64] bf16 (Q pre-scaled by 1/8).
// Y: [8192][512] bf16, col = h*64 + d.
__global__ __launch_bounds__(256,2) void attn_kernel(
    const unsigned short* __restrict__ Q,
    const unsigned short* __restrict__ K,
    const unsigned short* __restrict__ V,
    const float* __restrict__ alib,
    unsigned short* __restrict__ Y){
  __shared__ unsigned short Ks[64][72];
  __shared__ unsigned short Vt[64][72];
  __shared__ unsigned short Ps[4][32][72];
  const int tid = threadIdx.x, wid = tid >> 6, lane = tid & 63;
  const int fr = lane & 15, fq = lane >> 4;
  const int bh = blockIdx.y, h = bh & 7, b = bh >> 3;
  const int q0 = blockIdx.x * 128 + wid * 32;
  const unsigned short* Qp = Q + (size_t)bh * 131072;
  const unsigned short* Kp = K + (size_t)bh * 131072;
  const unsigned short* Vp = V + (size_t)bh * 131072;
  const float mh = -alib[(size_t)h * 4194304 + 1];   // slope m_h > 0

  bf16x8 qf[2][2];
  #pragma unroll
  for (int mi=0;mi<2;mi++)
    #pragma unroll
    for (int kk=0;kk<2;kk++)
      qf[mi][kk] = *(const bf16x8*)(Qp + (size_t)(q0 + mi*16 + fr)*64 + kk*32 + fq*8);

  f32x4 o[2][4];
  float mr[2][4], lr[2][4];
  #pragma unroll
  for (int mi=0;mi<2;mi++){
    #pragma unroll
    for (int ni=0;ni<4;ni++) o[mi][ni] = (f32x4){0.f,0.f,0.f,0.f};
    #pragma unroll
    for (int g=0;g<4;g++){ mr[mi][g] = -1e30f; lr[mi][g] = 0.f; }
  }

  const int srow = tid >> 2, scol = (tid & 3) * 8;
  for (int kt = 0; kt < 32; kt++){
    const int kb = kt * 64;
    __syncthreads();
    {
      const unsigned short* kr = Kp + (size_t)(kb + srow)*64 + scol;
      *(short8*)&Ks[srow][scol]      = *(const short8*)kr;
      *(short8*)&Ks[srow][scol + 32] = *(const short8*)(kr + 32);
      const unsigned short* vr = Vp + (size_t)(kb + srow)*64 + scol;
      short8 w0 = *(const short8*)vr;
      short8 w1 = *(const short8*)(vr + 32);
      #pragma unroll
      for (int j=0;j<8;j++){
        Vt[scol + j][srow]      = (unsigned short)w0[j];
        Vt[scol + 32 + j][srow] = (unsigned short)w1[j];
      }
    }
    __syncthreads();

    bf16x8 kf[4][2];
    #pragma unroll
    for (int ni=0;ni<4;ni++)
      #pragma unroll
      for (int kk=0;kk<2;kk++)
        kf[ni][kk] = *(const bf16x8*)&Ks[ni*16 + fr][kk*32 + fq*8];

    f32x4 s[2][4];
    const f32x4 fz = {0.f,0.f,0.f,0.f};
    #pragma unroll
    for (int mi=0;mi<2;mi++)
      #pragma unroll
      for (int ni=0;ni<4;ni++){
        f32x4 t0 = __builtin_amdgcn_mfma_f32_16x16x32_bf16(qf[mi][0], kf[ni][0], fz, 0,0,0);
        s[mi][ni] = __builtin_amdgcn_mfma_f32_16x16x32_bf16(qf[mi][1], kf[ni][1], t0, 0,0,0);
      }

    // ALiBi bias + online softmax (rows live in (fq,g); cols in (ni,fr))
    #pragma unroll
    for (int mi=0;mi<2;mi++){
      #pragma unroll
      for (int g=0;g<4;g++){
        const int qi = q0 + mi*16 + fq*4 + g;
        #pragma unroll
        for (int ni=0;ni<4;ni++){
          const int kj = kb + ni*16 + fr;
          const int dd = qi > kj ? qi - kj : kj - qi;
          s[mi][ni][g] -= mh * (float)dd;
        }
        float tm = fmaxf(fmaxf(s[mi][0][g], s[mi][1][g]), fmaxf(s[mi][2][g], s[mi][3][g]));
        #pragma unroll
        for (int d2=1; d2<16; d2<<=1) tm = fmaxf(tm, __shfl_xor(tm, d2));
        const float mn  = fmaxf(mr[mi][g], tm);
        const float scl = exp2f((mr[mi][g] - mn) * LOG2E);
        mr[mi][g] = mn;
        float rs = 0.f;
        #pragma unroll
        for (int ni=0;ni<4;ni++){
          const float p = exp2f((s[mi][ni][g] - mn) * LOG2E);
          s[mi][ni][g] = p;
          rs += p;
          o[mi][ni][g] *= scl;
        }
        #pragma unroll
        for (int d2=1; d2<16; d2<<=1) rs += __shfl_xor(rs, d2);
        lr[mi][g] = lr[mi][g] * scl + rs;
      }
    }

    // P -> LDS (D-layout positions), re-read in A-frag layout
    #pragma unroll
    for (int mi=0;mi<2;mi++)
      #pragma unroll
      for (int g=0;g<4;g++)
        #pragma unroll
        for (int ni=0;ni<4;ni++)
          Ps[wid][mi*16 + fq*4 + g][ni*16 + fr] = f2b(s[mi][ni][g]);

    bf16x8 pf[2][2], vf[4][2];
    #pragma unroll
    for (int mi=0;mi<2;mi++)
      #pragma unroll
      for (int kk=0;kk<2;kk++)
        pf[mi][kk] = *(const bf16x8*)&Ps[wid][mi*16 + fr][kk*32 + fq*8];
    #pragma unroll
    for (int ni=0;ni<4;ni++)
      #pragma unroll
      for (int kk=0;kk<2;kk++)
        vf[ni][kk] = *(const bf16x8*)&Vt[ni*16 + fr][kk*32 + fq*8];
    #pragma unroll
    for (int mi=0;mi<2;mi++)
      #pragma unroll
      for (int ni=0;ni<4;ni++){
        o[mi][ni] = __builtin_amdgcn_mfma_f32_16x16x32_bf16(pf[mi][0], vf[ni][0], o[mi][ni], 0,0,0);
        o[mi][ni] = __builtin_amdgcn_mfma_f32_16x16x32_bf16(pf[mi][1], vf[ni][1], o[mi][ni], 0,0,0);
      }
  }

  #pragma unroll
  for (int mi=0;mi<2;mi++)
    #pragma unroll
    for (int g=0;g<4;g++){
      const float inv = 1.0f / lr[mi][g];
      const int t = q0 + mi*16 + fq*4 + g;
      #pragma unroll
      for (int ni=0;ni<4;ni++)
        Y[(size_t)(b*2048 + t)*512 + h*64 + ni*16 + fr] = f2b(o[mi][ni][g] * inv);
    }
}

// ---------------- output projection GEMM ----------------
__global__ __launch_bounds__(256,2) void gemm_proj_kernel(
    const unsigned short* __restrict__ A,   // Yb [8192][512]
    const unsigned short* __restrict__ Bt,  // WprojT [512][512]
    const float* __restrict__ bias,         // bproj [512]
    float* __restrict__ out){
  __shared__ unsigned short As[128][40];
  __shared__ unsigned short Bs[128][40];
  const int tid = threadIdx.x, wid = tid >> 6, lane = tid & 63;
  const int wr = wid >> 1, wc = wid & 1;
  const int fr = lane & 15, fq = lane >> 4;
  const int bm = blockIdx.x * 128, bn = blockIdx.y * 128;
  const int srow = tid >> 2, scol = (tid & 3) * 8;
  f32x4 acc[4][4];
  #pragma unroll
  for (int m=0;m<4;m++)
    #pragma unroll
    for (int n=0;n<4;n++) acc[m][n] = (f32x4){0.f,0.f,0.f,0.f};

  for (int k0 = 0; k0 < 512; k0 += 32){
    __syncthreads();
    #pragma unroll
    for (int i=0;i<2;i++){
      int r = i*64 + srow;
      *(short8*)&As[r][scol] = *(const short8*)(A  + (size_t)(bm + r)*512 + k0 + scol);
      *(short8*)&Bs[r][scol] = *(const short8*)(Bt + (size_t)(bn + r)*512 + k0 + scol);
    }
    __syncthreads();
    bf16x8 af[4], bfv[4];
    #pragma unroll
    for (int m=0;m<4;m++) af[m]  = *(const bf16x8*)&As[wr*64 + m*16 + fr][fq*8];
    #pragma unroll
    for (int n=0;n<4;n++) bfv[n] = *(const bf16x8*)&Bs[wc*64 + n*16 + fr][fq*8];
    #pragma unroll
    for (int m=0;m<4;m++)
      #pragma unroll
      for (int n=0;n<4;n++)
        acc[m][n] = __builtin_amdgcn_mfma_f32_16x16x32_bf16(af[m], bfv[n], acc[m][n], 0,0,0);
  }

  #pragma unroll
  for (int m=0;m<4;m++){
    const int row0 = bm + wr*64 + m*16 + fq*4;
    #pragma unroll
    for (int n=0;n<4;n++){
      const int col = bn + wc*64 + n*16 + fr;
      const float bv = bias[col];
      #pragma unroll
      for (int g=0; g<4; g++)
        out[(size_t)(row0 + g)*512 + col] = acc[m][n][g] + bv;
    }
  }
}

// ---------------- launch ----------------
extern "C" void kernel_launch(void* const* d_in, const int* in_sizes, int n_in,
                              void* d_out, int out_size, void* d_ws, size_t ws_size,
                              hipStream_t stream){
  const float* x     = (const float*)d_in[0];
  const float* Wqkv  = (const float*)d_in[1];
  const float* bqkv  = (const float*)d_in[2];
  const float* Wproj = (const float*)d_in[3];
  const float* bproj = (const float*)d_in[4];
  const float* alib  = (const float*)d_in[5];
  char* ws = (char*)d_ws;
  unsigned short* xb     = (unsigned short*)(ws);
  unsigned short* wqkvT  = (unsigned short*)(ws + 8388608);
  unsigned short* wprojT = (unsigned short*)(ws + 9961472);
  unsigned short* Qb     = (unsigned short*)(ws + 10485760);
  unsigned short* Kb     = (unsigned short*)(ws + 18874368);
  unsigned short* Vb     = (unsigned short*)(ws + 27262976);
  unsigned short* Yb     = (unsigned short*)(ws + 35651584);
  float* out = (float*)d_out;

  cvt_x_kernel<<<2048, 256, 0, stream>>>(x, xb);
  cvt_tr_kernel<<<dim3(6, 512), 256, 0, stream>>>(Wqkv, wqkvT, 512, 1536);
  cvt_tr_kernel<<<dim3(2, 512), 256, 0, stream>>>(Wproj, wprojT, 512, 512);
  gemm_qkv_kernel<<<dim3(64, 12), 256, 0, stream>>>(xb, wqkvT, bqkv, Qb, Kb, Vb);
  attn_kernel<<<dim3(16, 32), 256, 0, stream>>>(Qb, Kb, Vb, alib, Yb);
  gemm_proj_kernel<<<dim3(64, 4), 256, 0, stream>>>(Yb, wprojT, bproj, out);
}

// Round 2
// 141.260 us; speedup vs baseline: 1.4659x; 1.4659x over previous
//
#include <hip/hip_runtime.h>
#include <hip/hip_bf16.h>

#define LOG2E 1.4426950408889634f

typedef __attribute__((ext_vector_type(8))) short short8;
typedef __attribute__((ext_vector_type(8))) __bf16 bf16x8;
typedef __attribute__((ext_vector_type(4))) float f32x4;

__device__ __forceinline__ unsigned short f2b(float f){
  unsigned int u = __builtin_bit_cast(unsigned int, f);
  u += 0x7fffu + ((u >> 16) & 1u);
  return (unsigned short)(u >> 16);
}

__device__ __forceinline__ unsigned int cvtpk(float lo, float hi){
  unsigned int r;
  asm("v_cvt_pk_bf16_f32 %0, %1, %2" : "=v"(r) : "v"(lo), "v"(hi));
  return r;
}

__device__ __forceinline__ void gload16(const void* g, void* l){
  __builtin_amdgcn_global_load_lds(
      (const __attribute__((address_space(1))) unsigned int*)g,
      (__attribute__((address_space(3))) unsigned int*)l, 16, 0, 0);
}

// ---------------- conversion kernels ----------------
__global__ __launch_bounds__(256) void cvt_x_kernel(const float* __restrict__ in,
                                                    unsigned short* __restrict__ out){
  size_t i = ((size_t)blockIdx.x * 256 + threadIdx.x) * 8;
  float4 a = *(const float4*)(in + i);
  float4 b = *(const float4*)(in + i + 4);
  short8 s;
  s[0]=(short)f2b(a.x); s[1]=(short)f2b(a.y); s[2]=(short)f2b(a.z); s[3]=(short)f2b(a.w);
  s[4]=(short)f2b(b.x); s[5]=(short)f2b(b.y); s[6]=(short)f2b(b.z); s[7]=(short)f2b(b.w);
  *(short8*)(out + i) = s;
}

// out[c][r] = in[r][c]  (build B^T bf16)
__global__ __launch_bounds__(256) void cvt_tr_kernel(const float* __restrict__ in,
                                                     unsigned short* __restrict__ out,
                                                     int R, int C){
  int c = blockIdx.x * 256 + threadIdx.x;
  int r = blockIdx.y;
  if (c < C) out[(size_t)c * R + r] = f2b(in[(size_t)r * C + c]);
}

// ---------------- QKV GEMM ----------------
// A: xb [8192][512] bf16.  Bt: WqkvT [1536][512] bf16.  bias: bqkv [1536] f32.
// Q [bh][t][64] scaled by 0.125*LOG2E; K [bh][t][64]; VT [bh][64][2048] (transposed).
__global__ __launch_bounds__(256,2) void gemm_qkv_kernel(
    const unsigned short* __restrict__ A,
    const unsigned short* __restrict__ Bt,
    const float* __restrict__ bias,
    unsigned short* __restrict__ Qb,
    unsigned short* __restrict__ Kb,
    unsigned short* __restrict__ VTb){
  __shared__ unsigned short As[128][40];
  __shared__ unsigned short Bs[128][40];
  const int tid = threadIdx.x, wid = tid >> 6, lane = tid & 63;
  const int wr = wid >> 1, wc = wid & 1;
  const int fr = lane & 15, fq = lane >> 4;
  const int bm = blockIdx.x * 128, bn = blockIdx.y * 128;
  const int srow = tid >> 2, scol = (tid & 3) * 8;
  f32x4 acc[4][4];
  #pragma unroll
  for (int m=0;m<4;m++)
    #pragma unroll
    for (int n=0;n<4;n++) acc[m][n] = (f32x4){0.f,0.f,0.f,0.f};

  for (int k0 = 0; k0 < 512; k0 += 32){
    __syncthreads();
    #pragma unroll
    for (int i=0;i<2;i++){
      int r = i*64 + srow;
      *(short8*)&As[r][scol] = *(const short8*)(A  + (size_t)(bm + r)*512 + k0 + scol);
      *(short8*)&Bs[r][scol] = *(const short8*)(Bt + (size_t)(bn + r)*512 + k0 + scol);
    }
    __syncthreads();
    bf16x8 af[4], bfv[4];
    #pragma unroll
    for (int m=0;m<4;m++) af[m]  = *(const bf16x8*)&As[wr*64 + m*16 + fr][fq*8];
    #pragma unroll
    for (int n=0;n<4;n++) bfv[n] = *(const bf16x8*)&Bs[wc*64 + n*16 + fr][fq*8];
    #pragma unroll
    for (int m=0;m<4;m++)
      #pragma unroll
      for (int n=0;n<4;n++)
        acc[m][n] = __builtin_amdgcn_mfma_f32_16x16x32_bf16(af[m], bfv[n], acc[m][n], 0,0,0);
  }

  const float SCQ = 0.125f * LOG2E;
  #pragma unroll
  for (int m=0;m<4;m++){
    const int row0 = bm + wr*64 + m*16 + fq*4;
    const int b_ = row0 >> 11, t_ = row0 & 2047;
    #pragma unroll
    for (int n=0;n<4;n++){
      const int col = bn + wc*64 + n*16 + fr;
      const int which = col >> 9, c = col & 511, hh = c >> 6, dd = c & 63;
      const float bv = bias[col];
      if (which == 0){
        #pragma unroll
        for (int g=0; g<4; g++)
          Qb[((size_t)(b_*8 + hh)*2048 + t_ + g)*64 + dd] = f2b((acc[m][n][g] + bv)*SCQ);
      } else if (which == 1){
        #pragma unroll
        for (int g=0; g<4; g++)
          Kb[((size_t)(b_*8 + hh)*2048 + t_ + g)*64 + dd] = f2b(acc[m][n][g] + bv);
      } else {
        uint2 pk;
        pk.x = cvtpk(acc[m][n][0] + bv, acc[m][n][1] + bv);
        pk.y = cvtpk(acc[m][n][2] + bv, acc[m][n][3] + bv);
        *(uint2*)&VTb[((size_t)(b_*8 + hh)*64 + dd)*2048 + t_] = pk;
      }
    }
  }
}

// ---------------- flash attention (S^T formulation) ----------------
// Q [bh][2048][64] bf16 (pre-scaled by 0.125*LOG2E), K [bh][2048][64], VT [bh][64][2048].
// Y: [8192][512] bf16, col = h*64 + d.
__global__ __launch_bounds__(256,2) void attn_kernel(
    const unsigned short* __restrict__ Q,
    const unsigned short* __restrict__ K,
    const unsigned short* __restrict__ VT,
    const float* __restrict__ alib,
    unsigned short* __restrict__ Y){
  __shared__ unsigned short Ks[64*64];
  __shared__ unsigned short Vs[64*64];
  __shared__ unsigned short Ps[4][32][72];
  const int tid = threadIdx.x, wid = tid >> 6, lane = tid & 63;
  const int fr = lane & 15, fq = lane >> 4;
  const int fr7 = fr & 7;
  const int bh = blockIdx.y, h = bh & 7, b = bh >> 3;
  const int q0 = blockIdx.x * 128 + wid * 32;
  const unsigned short* Qp = Q  + (size_t)bh * 131072;
  const unsigned short* Kp = K  + (size_t)bh * 131072;
  const unsigned short* Vp = VT + (size_t)bh * 131072;
  const float nmh2 = alib[(size_t)h * 4194304 + 1] * LOG2E;  // = -m_h*log2e (negative)

  // hoisted Q fragments (B-frag == row-major row read)
  bf16x8 qf[2][2];
  #pragma unroll
  for (int mi=0;mi<2;mi++)
    #pragma unroll
    for (int kk=0;kk<2;kk++)
      qf[mi][kk] = *(const bf16x8*)(Qp + (size_t)(q0 + mi*16 + fr)*64 + kk*32 + fq*8);

  f32x4 o[2][4];
  #pragma unroll
  for (int mi=0;mi<2;mi++)
    #pragma unroll
    for (int ni=0;ni<4;ni++) o[mi][ni] = (f32x4){0.f,0.f,0.f,0.f};
  float mr[2] = {-1e30f, -1e30f}, lr[2] = {0.f, 0.f};
  const float qif[2] = {(float)(q0 + fr), (float)(q0 + 16 + fr)};

  for (int kt = 0; kt < 32; kt++){
    const int kb = kt * 64;
    __syncthreads();
    // stage K tile [kv][64] and V^T tile [d][kv-range], xor-swizzled source
    #pragma unroll
    for (int it=0; it<2; it++){
      const int s = it*256 + tid;
      const int row = s >> 3, c = s & 7;
      const int sc = c ^ (row & 7);
      void* kl = (void*)(Ks + (it*256 + wid*64)*8);
      void* vl = (void*)(Vs + (it*256 + wid*64)*8);
      gload16(Kp + (size_t)(kb + row)*64 + sc*8, kl);
      gload16(Vp + (size_t)row*2048 + kb + sc*8, vl);
    }
    __syncthreads();

    bf16x8 kf[4][2], vf[4][2];
    #pragma unroll
    for (int ni=0;ni<4;ni++)
      #pragma unroll
      for (int kk=0;kk<2;kk++){
        const int r = ni*16 + fr;
        const int sw = ((kk*4 + fq) ^ fr7) * 8;
        kf[ni][kk] = *(const bf16x8*)&Ks[r*64 + sw];
        vf[ni][kk] = *(const bf16x8*)&Vs[r*64 + sw];
      }

    // S^T = K·Q^T : lane holds col q = q0+mi*16+fr, rows kv = kb+ni*16+fq*4+g
    f32x4 st[2][4];
    const f32x4 fz = {0.f,0.f,0.f,0.f};
    #pragma unroll
    for (int mi=0;mi<2;mi++)
      #pragma unroll
      for (int ni=0;ni<4;ni++){
        f32x4 t0 = __builtin_amdgcn_mfma_f32_16x16x32_bf16(kf[ni][0], qf[mi][0], fz, 0,0,0);
        st[mi][ni] = __builtin_amdgcn_mfma_f32_16x16x32_bf16(kf[ni][1], qf[mi][1], t0, 0,0,0);
      }

    float scl_[2];
    #pragma unroll
    for (int mi=0;mi<2;mi++){
      const float base = qif[mi] - (float)(kb + fq*4);
      // ALiBi bias: st += nmh2 * |qi - kj|   (log2 domain)
      #pragma unroll
      for (int ni=0;ni<4;ni++)
        #pragma unroll
        for (int g=0;g<4;g++){
          const float d = fabsf(base - (float)(ni*16 + g));
          st[mi][ni][g] = fmaf(nmh2, d, st[mi][ni][g]);
        }
      // in-lane max tree over 16 values
      float m0 = fmaxf(fmaxf(st[mi][0][0], st[mi][0][1]), fmaxf(st[mi][0][2], st[mi][0][3]));
      float m1 = fmaxf(fmaxf(st[mi][1][0], st[mi][1][1]), fmaxf(st[mi][1][2], st[mi][1][3]));
      float m2 = fmaxf(fmaxf(st[mi][2][0], st[mi][2][1]), fmaxf(st[mi][2][2], st[mi][2][3]));
      float m3 = fmaxf(fmaxf(st[mi][3][0], st[mi][3][1]), fmaxf(st[mi][3][2], st[mi][3][3]));
      float tm = fmaxf(fmaxf(m0, m1), fmaxf(m2, m3));
      tm = fmaxf(tm, __shfl_xor(tm, 16));
      tm = fmaxf(tm, __shfl_xor(tm, 32));
      const float mn = fmaxf(mr[mi], tm);
      const float sc = exp2f(mr[mi] - mn);
      mr[mi] = mn;
      float rs = 0.f;
      #pragma unroll
      for (int ni=0;ni<4;ni++){
        #pragma unroll
        for (int g=0;g<4;g++){
          const float p = exp2f(st[mi][ni][g] - mn);
          st[mi][ni][g] = p;
          rs += p;
        }
      }
      rs += __shfl_xor(rs, 16);
      rs += __shfl_xor(rs, 32);
      lr[mi] = lr[mi]*sc + rs;
      scl_[mi] = sc;
      // pack P -> per-wave LDS (A-frag layout source)
      #pragma unroll
      for (int ni=0;ni<4;ni++){
        uint2 pk;
        pk.x = cvtpk(st[mi][ni][0], st[mi][ni][1]);
        pk.y = cvtpk(st[mi][ni][2], st[mi][ni][3]);
        *(uint2*)&Ps[wid][mi*16 + fr][ni*16 + fq*4] = pk;
      }
    }

    // rescale O rows (row q = mi*16 + fq*4 + g; scl held by lane fr = fq*4+g)
    #pragma unroll
    for (int mi=0;mi<2;mi++)
      #pragma unroll
      for (int g=0;g<4;g++){
        const float sv = __shfl(scl_[mi], fq*4 + g);
        #pragma unroll
        for (int ni=0;ni<4;ni++) o[mi][ni][g] *= sv;
      }

    // PV: O += P·V  (A-frag from per-wave Ps, B-frag = rows of V^T)
    bf16x8 pf[2][2];
    #pragma unroll
    for (int mi=0;mi<2;mi++)
      #pragma unroll
      for (int kk=0;kk<2;kk++)
        pf[mi][kk] = *(const bf16x8*)&Ps[wid][mi*16 + fr][kk*32 + fq*8];
    #pragma unroll
    for (int mi=0;mi<2;mi++)
      #pragma unroll
      for (int ni=0;ni<4;ni++){
        o[mi][ni] = __builtin_amdgcn_mfma_f32_16x16x32_bf16(pf[mi][0], vf[ni][0], o[mi][ni], 0,0,0);
        o[mi][ni] = __builtin_amdgcn_mfma_f32_16x16x32_bf16(pf[mi][1], vf[ni][1], o[mi][ni], 0,0,0);
      }
  }

  // epilogue: normalize and store
  #pragma unroll
  for (int mi=0;mi<2;mi++){
    const float inv = 1.0f / lr[mi];
    #pragma unroll
    for (int g=0;g<4;g++){
      const float iv = __shfl(inv, fq*4 + g);
      const int t = q0 + mi*16 + fq*4 + g;
      #pragma unroll
      for (int ni=0;ni<4;ni++)
        Y[(size_t)(b*2048 + t)*512 + h*64 + ni*16 + fr] = f2b(o[mi][ni][g] * iv);
    }
  }
}

// ---------------- output projection GEMM ----------------
__global__ __launch_bounds__(256,2) void gemm_proj_kernel(
    const unsigned short* __restrict__ A,   // Yb [8192][512]
    const unsigned short* __restrict__ Bt,  // WprojT [512][512]
    const float* __restrict__ bias,         // bproj [512]
    float* __restrict__ out){
  __shared__ unsigned short As[128][40];
  __shared__ unsigned short Bs[128][40];
  const int tid = threadIdx.x, wid = tid >> 6, lane = tid & 63;
  const int wr = wid >> 1, wc = wid & 1;
  const int fr = lane & 15, fq = lane >> 4;
  const int bm = blockIdx.x * 128, bn = blockIdx.y * 128;
  const int srow = tid >> 2, scol = (tid & 3) * 8;
  f32x4 acc[4][4];
  #pragma unroll
  for (int m=0;m<4;m++)
    #pragma unroll
    for (int n=0;n<4;n++) acc[m][n] = (f32x4){0.f,0.f,0.f,0.f};

  for (int k0 = 0; k0 < 512; k0 += 32){
    __syncthreads();
    #pragma unroll
    for (int i=0;i<2;i++){
      int r = i*64 + srow;
      *(short8*)&As[r][scol] = *(const short8*)(A  + (size_t)(bm + r)*512 + k0 + scol);
      *(short8*)&Bs[r][scol] = *(const short8*)(Bt + (size_t)(bn + r)*512 + k0 + scol);
    }
    __syncthreads();
    bf16x8 af[4], bfv[4];
    #pragma unroll
    for (int m=0;m<4;m++) af[m]  = *(const bf16x8*)&As[wr*64 + m*16 + fr][fq*8];
    #pragma unroll
    for (int n=0;n<4;n++) bfv[n] = *(const bf16x8*)&Bs[wc*64 + n*16 + fr][fq*8];
    #pragma unroll
    for (int m=0;m<4;m++)
      #pragma unroll
      for (int n=0;n<4;n++)
        acc[m][n] = __builtin_amdgcn_mfma_f32_16x16x32_bf16(af[m], bfv[n], acc[m][n], 0,0,0);
  }

  #pragma unroll
  for (int m=0;m<4;m++){
    const int row0 = bm + wr*64 + m*16 + fq*4;
    #pragma unroll
    for (int n=0;n<4;n++){
      const int col = bn + wc*64 + n*16 + fr;
      const float bv = bias[col];
      #pragma unroll
      for (int g=0; g<4; g++)
        out[(size_t)(row0 + g)*512 + col] = acc[m][n][g] + bv;
    }
  }
}

// ---------------- launch ----------------
extern "C" void kernel_launch(void* const* d_in, const int* in_sizes, int n_in,
                              void* d_out, int out_size, void* d_ws, size_t ws_size,
                              hipStream_t stream){
  const float* x     = (const float*)d_in[0];
  const float* Wqkv  = (const float*)d_in[1];
  const float* bqkv  = (const float*)d_in[2];
  const float* Wproj = (const float*)d_in[3];
  const float* bproj = (const float*)d_in[4];
  const float* alib  = (const float*)d_in[5];
  char* ws = (char*)d_ws;
  unsigned short* xb     = (unsigned short*)(ws);
  unsigned short* wqkvT  = (unsigned short*)(ws + 8388608);
  unsigned short* wprojT = (unsigned short*)(ws + 9961472);
  unsigned short* Qb     = (unsigned short*)(ws + 10485760);
  unsigned short* Kb     = (unsigned short*)(ws + 18874368);
  unsigned short* VTb    = (unsigned short*)(ws + 27262976);
  unsigned short* Yb     = (unsigned short*)(ws + 35651584);
  float* out = (float*)d_out;

  cvt_x_kernel<<<2048, 256, 0, stream>>>(x, xb);
  cvt_tr_kernel<<<dim3(6, 512), 256, 0, stream>>>(Wqkv, wqkvT, 512, 1536);
  cvt_tr_kernel<<<dim3(2, 512), 256, 0, stream>>>(Wproj, wprojT, 512, 512);
  gemm_qkv_kernel<<<dim3(64, 12), 256, 0, stream>>>(xb, wqkvT, bqkv, Qb, Kb, VTb);
  attn_kernel<<<dim3(16, 32), 256, 0, stream>>>(Qb, Kb, VTb, alib, Yb);
  gemm_proj_kernel<<<dim3(64, 4), 256, 0, stream>>>(Yb, wprojT, bproj, out);
}

// Round 3
// 104.577 us; speedup vs baseline: 1.9802x; 1.3508x over previous
//
#include <hip/hip_runtime.h>
#include <hip/hip_bf16.h>

#define LOG2E 1.4426950408889634f

typedef __attribute__((ext_vector_type(8))) short short8;
typedef __attribute__((ext_vector_type(8))) __bf16 bf16x8;
typedef __attribute__((ext_vector_type(4))) float f32x4;

__device__ __forceinline__ unsigned short f2b(float f){
  unsigned int u = __builtin_bit_cast(unsigned int, f);
  u += 0x7fffu + ((u >> 16) & 1u);
  return (unsigned short)(u >> 16);
}

__device__ __forceinline__ float b2f(unsigned short s){
  unsigned int u = ((unsigned int)s) << 16;
  return __builtin_bit_cast(float, u);
}

__device__ __forceinline__ unsigned int cvtpk(float lo, float hi){
  unsigned int r;
  asm("v_cvt_pk_bf16_f32 %0, %1, %2" : "=v"(r) : "v"(lo), "v"(hi));
  return r;
}

__device__ __forceinline__ void gload16(const void* g, void* l){
  __builtin_amdgcn_global_load_lds(
      (const __attribute__((address_space(1))) unsigned int*)g,
      (__attribute__((address_space(3))) unsigned int*)l, 16, 0, 0);
}

// ---------------- conversion kernels ----------------
__global__ __launch_bounds__(256) void cvt_x_kernel(const float* __restrict__ in,
                                                    unsigned short* __restrict__ out){
  size_t i = ((size_t)blockIdx.x * 256 + threadIdx.x) * 8;
  float4 a = *(const float4*)(in + i);
  float4 b = *(const float4*)(in + i + 4);
  short8 s;
  s[0]=(short)f2b(a.x); s[1]=(short)f2b(a.y); s[2]=(short)f2b(a.z); s[3]=(short)f2b(a.w);
  s[4]=(short)f2b(b.x); s[5]=(short)f2b(b.y); s[6]=(short)f2b(b.z); s[7]=(short)f2b(b.w);
  *(short8*)(out + i) = s;
}

// out[c][r] = in[r][c]  (build B^T bf16)
__global__ __launch_bounds__(256) void cvt_tr_kernel(const float* __restrict__ in,
                                                     unsigned short* __restrict__ out,
                                                     int R, int C){
  int c = blockIdx.x * 256 + threadIdx.x;
  int r = blockIdx.y;
  if (c < C) out[(size_t)c * R + r] = f2b(in[(size_t)r * C + c]);
}

// ---------------- QKV GEMM ----------------
__global__ __launch_bounds__(256,2) void gemm_qkv_kernel(
    const unsigned short* __restrict__ A,
    const unsigned short* __restrict__ Bt,
    const float* __restrict__ bias,
    unsigned short* __restrict__ Qb,
    unsigned short* __restrict__ Kb,
    unsigned short* __restrict__ VTb){
  __shared__ unsigned short As[128][40];
  __shared__ unsigned short Bs[128][40];
  const int tid = threadIdx.x, wid = tid >> 6, lane = tid & 63;
  const int wr = wid >> 1, wc = wid & 1;
  const int fr = lane & 15, fq = lane >> 4;
  const int bm = blockIdx.x * 128, bn = blockIdx.y * 128;
  const int srow = tid >> 2, scol = (tid & 3) * 8;
  f32x4 acc[4][4];
  #pragma unroll
  for (int m=0;m<4;m++)
    #pragma unroll
    for (int n=0;n<4;n++) acc[m][n] = (f32x4){0.f,0.f,0.f,0.f};

  for (int k0 = 0; k0 < 512; k0 += 32){
    __syncthreads();
    #pragma unroll
    for (int i=0;i<2;i++){
      int r = i*64 + srow;
      *(short8*)&As[r][scol] = *(const short8*)(A  + (size_t)(bm + r)*512 + k0 + scol);
      *(short8*)&Bs[r][scol] = *(const short8*)(Bt + (size_t)(bn + r)*512 + k0 + scol);
    }
    __syncthreads();
    bf16x8 af[4], bfv[4];
    #pragma unroll
    for (int m=0;m<4;m++) af[m]  = *(const bf16x8*)&As[wr*64 + m*16 + fr][fq*8];
    #pragma unroll
    for (int n=0;n<4;n++) bfv[n] = *(const bf16x8*)&Bs[wc*64 + n*16 + fr][fq*8];
    #pragma unroll
    for (int m=0;m<4;m++)
      #pragma unroll
      for (int n=0;n<4;n++)
        acc[m][n] = __builtin_amdgcn_mfma_f32_16x16x32_bf16(af[m], bfv[n], acc[m][n], 0,0,0);
  }

  const float SCQ = 0.125f * LOG2E;
  #pragma unroll
  for (int m=0;m<4;m++){
    const int row0 = bm + wr*64 + m*16 + fq*4;
    const int b_ = row0 >> 11, t_ = row0 & 2047;
    #pragma unroll
    for (int n=0;n<4;n++){
      const int col = bn + wc*64 + n*16 + fr;
      const int which = col >> 9, c = col & 511, hh = c >> 6, dd = c & 63;
      const float bv = bias[col];
      if (which == 0){
        #pragma unroll
        for (int g=0; g<4; g++)
          Qb[((size_t)(b_*8 + hh)*2048 + t_ + g)*64 + dd] = f2b((acc[m][n][g] + bv)*SCQ);
      } else if (which == 1){
        #pragma unroll
        for (int g=0; g<4; g++)
          Kb[((size_t)(b_*8 + hh)*2048 + t_ + g)*64 + dd] = f2b(acc[m][n][g] + bv);
      } else {
        uint2 pk;
        pk.x = cvtpk(acc[m][n][0] + bv, acc[m][n][1] + bv);
        pk.y = cvtpk(acc[m][n][2] + bv, acc[m][n][3] + bv);
        *(uint2*)&VTb[((size_t)(b_*8 + hh)*64 + dd)*2048 + t_] = pk;
      }
    }
  }
}

// ---------------- norm prepass ----------------
// Per (bh, 64-row chunk): Mq = max_row ||q_scaled||, Mk = max_row ||k||.
__global__ __launch_bounds__(128) void norms_kernel(
    const unsigned short* __restrict__ Q,
    const unsigned short* __restrict__ K,
    float* __restrict__ Mq, float* __restrict__ Mk){
  __shared__ float red[2];
  const int ch = blockIdx.x, bh = blockIdx.y;
  const int tid = threadIdx.x, wid = tid >> 6;
  const int row = tid >> 1, half = (tid & 1) * 32;
  #pragma unroll
  for (int s = 0; s < 2; s++){
    const unsigned short* base = (s ? K : Q) + (size_t)bh * 131072 + (size_t)(ch*64 + row)*64 + half;
    float ss = 0.f;
    #pragma unroll
    for (int j=0;j<4;j++){
      short8 v = *(const short8*)(base + j*8);
      #pragma unroll
      for (int e=0;e<8;e++){
        float f = b2f((unsigned short)v[e]);
        ss = fmaf(f, f, ss);
      }
    }
    ss += __shfl_xor(ss, 1);
    float m = ss;
    #pragma unroll
    for (int d=2; d<64; d<<=1) m = fmaxf(m, __shfl_xor(m, d));
    if ((tid & 63) == 0) red[wid] = m;
    __syncthreads();
    if (tid == 0)
      (s ? Mk : Mq)[bh*32 + ch] = sqrtf(fmaxf(red[0], red[1]));
    __syncthreads();
  }
}

// ---------------- windowed flash attention (S^T formulation) ----------------
// 2-wave blocks, 64 q-rows. Diagonal-first ring order + norm-bound tile skipping.
__global__ __launch_bounds__(128,2) void attn_kernel(
    const unsigned short* __restrict__ Q,
    const unsigned short* __restrict__ K,
    const unsigned short* __restrict__ VT,
    const float* __restrict__ alib,
    const float* __restrict__ Mqa,
    const float* __restrict__ Mka,
    unsigned short* __restrict__ Y){
  __shared__ unsigned short Ks[64*64];
  __shared__ unsigned short Vs[64*64];
  __shared__ unsigned short Ps[2][32][72];
  __shared__ float MkS[32];
  __shared__ float wred[2];
  const int tid = threadIdx.x, wid = tid >> 6, lane = tid & 63;
  const int fr = lane & 15, fq = lane >> 4;
  const int fr7 = fr & 7;
  // LPT mapping: ascending id = costly heads (small h) first
  const int id = blockIdx.x;
  const int h = id >> 7, r_ = id & 127, b = r_ >> 5, qc = r_ & 31;
  const int bh = b*8 + h;
  const int q0 = qc*64 + wid*32;
  const unsigned short* Qp = Q  + (size_t)bh * 131072;
  const unsigned short* Kp = K  + (size_t)bh * 131072;
  const unsigned short* Vp = VT + (size_t)bh * 131072;
  const float nmh2 = alib[(size_t)h * 4194304 + 1] * LOG2E;  // = -m_h*log2e (negative)
  const float MqMk0 = Mqa[bh*32 + qc];
  if (tid < 32) MkS[tid] = Mka[bh*32 + tid];

  bf16x8 qf[2][2];
  #pragma unroll
  for (int mi=0;mi<2;mi++)
    #pragma unroll
    for (int kk=0;kk<2;kk++)
      qf[mi][kk] = *(const bf16x8*)(Qp + (size_t)(q0 + mi*16 + fr)*64 + kk*32 + fq*8);

  f32x4 o[2][4];
  #pragma unroll
  for (int mi=0;mi<2;mi++)
    #pragma unroll
    for (int ni=0;ni<4;ni++) o[mi][ni] = (f32x4){0.f,0.f,0.f,0.f};
  float mr[2] = {-1e30f, -1e30f}, lr[2] = {0.f, 0.f};
  const float qif[2] = {(float)(q0 + fr), (float)(q0 + 16 + fr)};

  auto process = [&](int kt){
    const int kb = kt * 64;
    __syncthreads();
    #pragma unroll
    for (int it=0; it<4; it++){
      const int s = it*128 + tid;
      const int row = s >> 3, c = s & 7;
      const int sc = c ^ (row & 7);
      void* kl = (void*)(Ks + (it*128 + wid*64)*8);
      void* vl = (void*)(Vs + (it*128 + wid*64)*8);
      gload16(Kp + (size_t)(kb + row)*64 + sc*8, kl);
      gload16(Vp + (size_t)row*2048 + kb + sc*8, vl);
    }
    __syncthreads();

    bf16x8 kf[4][2], vf[4][2];
    #pragma unroll
    for (int ni=0;ni<4;ni++)
      #pragma unroll
      for (int kk=0;kk<2;kk++){
        const int r = ni*16 + fr;
        const int sw = ((kk*4 + fq) ^ fr7) * 8;
        kf[ni][kk] = *(const bf16x8*)&Ks[r*64 + sw];
        vf[ni][kk] = *(const bf16x8*)&Vs[r*64 + sw];
      }

    f32x4 st[2][4];
    const f32x4 fz = {0.f,0.f,0.f,0.f};
    #pragma unroll
    for (int mi=0;mi<2;mi++)
      #pragma unroll
      for (int ni=0;ni<4;ni++){
        f32x4 t0 = __builtin_amdgcn_mfma_f32_16x16x32_bf16(kf[ni][0], qf[mi][0], fz, 0,0,0);
        st[mi][ni] = __builtin_amdgcn_mfma_f32_16x16x32_bf16(kf[ni][1], qf[mi][1], t0, 0,0,0);
      }

    #pragma unroll
    for (int mi=0;mi<2;mi++){
      const float base = qif[mi] - (float)(kb + fq*4);
      #pragma unroll
      for (int ni=0;ni<4;ni++)
        #pragma unroll
        for (int g=0;g<4;g++){
          const float d = fabsf(base - (float)(ni*16 + g));
          st[mi][ni][g] = fmaf(nmh2, d, st[mi][ni][g]);
        }
      float m0 = fmaxf(fmaxf(st[mi][0][0], st[mi][0][1]), fmaxf(st[mi][0][2], st[mi][0][3]));
      float m1 = fmaxf(fmaxf(st[mi][1][0], st[mi][1][1]), fmaxf(st[mi][1][2], st[mi][1][3]));
      float m2 = fmaxf(fmaxf(st[mi][2][0], st[mi][2][1]), fmaxf(st[mi][2][2], st[mi][2][3]));
      float m3 = fmaxf(fmaxf(st[mi][3][0], st[mi][3][1]), fmaxf(st[mi][3][2], st[mi][3][3]));
      float tm = fmaxf(fmaxf(m0, m1), fmaxf(m2, m3));
      tm = fmaxf(tm, __shfl_xor(tm, 16));
      tm = fmaxf(tm, __shfl_xor(tm, 32));

      const bool nog = __all(tm <= mr[mi]);
      float mn, sc;
      if (nog){
        mn = mr[mi];
      } else {
        mn = fmaxf(mr[mi], tm);
        sc = exp2f(mr[mi] - mn);
        mr[mi] = mn;
      }
      float rs = 0.f;
      #pragma unroll
      for (int ni=0;ni<4;ni++){
        #pragma unroll
        for (int g=0;g<4;g++){
          const float p = exp2f(st[mi][ni][g] - mn);
          st[mi][ni][g] = p;
          rs += p;
        }
      }
      rs += __shfl_xor(rs, 16);
      rs += __shfl_xor(rs, 32);
      if (nog){
        lr[mi] += rs;
      } else {
        lr[mi] = lr[mi]*sc + rs;
        #pragma unroll
        for (int g=0;g<4;g++){
          const float sv = __shfl(sc, fq*4 + g);
          #pragma unroll
          for (int ni=0;ni<4;ni++) o[mi][ni][g] *= sv;
        }
      }
      #pragma unroll
      for (int ni=0;ni<4;ni++){
        uint2 pk;
        pk.x = cvtpk(st[mi][ni][0], st[mi][ni][1]);
        pk.y = cvtpk(st[mi][ni][2], st[mi][ni][3]);
        *(uint2*)&Ps[wid][mi*16 + fr][ni*16 + fq*4] = pk;
      }
    }

    bf16x8 pf[2][2];
    #pragma unroll
    for (int mi=0;mi<2;mi++)
      #pragma unroll
      for (int kk=0;kk<2;kk++)
        pf[mi][kk] = *(const bf16x8*)&Ps[wid][mi*16 + fr][kk*32 + fq*8];
    #pragma unroll
    for (int mi=0;mi<2;mi++)
      #pragma unroll
      for (int ni=0;ni<4;ni++){
        o[mi][ni] = __builtin_amdgcn_mfma_f32_16x16x32_bf16(pf[mi][0], vf[ni][0], o[mi][ni], 0,0,0);
        o[mi][ni] = __builtin_amdgcn_mfma_f32_16x16x32_bf16(pf[mi][1], vf[ni][1], o[mi][ni], 0,0,0);
      }
  };

  auto refresh = [&](float* thr){
    float m = fminf(mr[0], mr[1]);
    #pragma unroll
    for (int d=1; d<16; d<<=1) m = fminf(m, __shfl_xor(m, d));
    if (lane == 0) wred[wid] = m;
    __syncthreads();
    *thr = fminf(wred[0], wred[1]) - 20.0f;
  };

  // diagonal tile first (always processed)
  process(qc);
  float thresh;
  refresh(&thresh);

  // ring expansion with norm-bound skipping
  for (int dt = 1; dt < 32; dt++){
    const float dmin = (float)((dt - 1)*64 + 1);
    const float biasmax = nmh2 * dmin;
    int kt = qc + dt;
    if (kt < 32 && MqMk0 * MkS[kt] + biasmax >= thresh) process(kt);
    kt = qc - dt;
    if (kt >= 0 && MqMk0 * MkS[kt] + biasmax >= thresh) process(kt);
    if (dt == 1) refresh(&thresh);
  }

  #pragma unroll
  for (int mi=0;mi<2;mi++){
    const float inv = 1.0f / lr[mi];
    #pragma unroll
    for (int g=0;g<4;g++){
      const float iv = __shfl(inv, fq*4 + g);
      const int t = q0 + mi*16 + fq*4 + g;
      #pragma unroll
      for (int ni=0;ni<4;ni++)
        Y[(size_t)(b*2048 + t)*512 + h*64 + ni*16 + fr] = f2b(o[mi][ni][g] * iv);
    }
  }
}

// ---------------- output projection GEMM ----------------
__global__ __launch_bounds__(256,2) void gemm_proj_kernel(
    const unsigned short* __restrict__ A,
    const unsigned short* __restrict__ Bt,
    const float* __restrict__ bias,
    float* __restrict__ out){
  __shared__ unsigned short As[128][40];
  __shared__ unsigned short Bs[128][40];
  const int tid = threadIdx.x, wid = tid >> 6, lane = tid & 63;
  const int wr = wid >> 1, wc = wid & 1;
  const int fr = lane & 15, fq = lane >> 4;
  const int bm = blockIdx.x * 128, bn = blockIdx.y * 128;
  const int srow = tid >> 2, scol = (tid & 3) * 8;
  f32x4 acc[4][4];
  #pragma unroll
  for (int m=0;m<4;m++)
    #pragma unroll
    for (int n=0;n<4;n++) acc[m][n] = (f32x4){0.f,0.f,0.f,0.f};

  for (int k0 = 0; k0 < 512; k0 += 32){
    __syncthreads();
    #pragma unroll
    for (int i=0;i<2;i++){
      int r = i*64 + srow;
      *(short8*)&As[r][scol] = *(const short8*)(A  + (size_t)(bm + r)*512 + k0 + scol);
      *(short8*)&Bs[r][scol] = *(const short8*)(Bt + (size_t)(bn + r)*512 + k0 + scol);
    }
    __syncthreads();
    bf16x8 af[4], bfv[4];
    #pragma unroll
    for (int m=0;m<4;m++) af[m]  = *(const bf16x8*)&As[wr*64 + m*16 + fr][fq*8];
    #pragma unroll
    for (int n=0;n<4;n++) bfv[n] = *(const bf16x8*)&Bs[wc*64 + n*16 + fr][fq*8];
    #pragma unroll
    for (int m=0;m<4;m++)
      #pragma unroll
      for (int n=0;n<4;n++)
        acc[m][n] = __builtin_amdgcn_mfma_f32_16x16x32_bf16(af[m], bfv[n], acc[m][n], 0,0,0);
  }

  #pragma unroll
  for (int m=0;m<4;m++){
    const int row0 = bm + wr*64 + m*16 + fq*4;
    #pragma unroll
    for (int n=0;n<4;n++){
      const int col = bn + wc*64 + n*16 + fr;
      const float bv = bias[col];
      #pragma unroll
      for (int g=0; g<4; g++)
        out[(size_t)(row0 + g)*512 + col] = acc[m][n][g] + bv;
    }
  }
}

// ---------------- launch ----------------
extern "C" void kernel_launch(void* const* d_in, const int* in_sizes, int n_in,
                              void* d_out, int out_size, void* d_ws, size_t ws_size,
                              hipStream_t stream){
  const float* x     = (const float*)d_in[0];
  const float* Wqkv  = (const float*)d_in[1];
  const float* bqkv  = (const float*)d_in[2];
  const float* Wproj = (const float*)d_in[3];
  const float* bproj = (const float*)d_in[4];
  const float* alib  = (const float*)d_in[5];
  char* ws = (char*)d_ws;
  unsigned short* xb     = (unsigned short*)(ws);
  unsigned short* wqkvT  = (unsigned short*)(ws + 8388608);
  unsigned short* wprojT = (unsigned short*)(ws + 9961472);
  unsigned short* Qb     = (unsigned short*)(ws + 10485760);
  unsigned short* Kb     = (unsigned short*)(ws + 18874368);
  unsigned short* VTb    = (unsigned short*)(ws + 27262976);
  unsigned short* Yb     = (unsigned short*)(ws + 35651584);
  float* out = (float*)d_out;
  // norm tables live in the tail of d_out; proj overwrites them afterwards
  float* Mq = out + 4194304 - 2048;
  float* Mk = Mq + 1024;

  cvt_x_kernel<<<2048, 256, 0, stream>>>(x, xb);
  cvt_tr_kernel<<<dim3(6, 512), 256, 0, stream>>>(Wqkv, wqkvT, 512, 1536);
  cvt_tr_kernel<<<dim3(2, 512), 256, 0, stream>>>(Wproj, wprojT, 512, 512);
  gemm_qkv_kernel<<<dim3(64, 12), 256, 0, stream>>>(xb, wqkvT, bqkv, Qb, Kb, VTb);
  norms_kernel<<<dim3(32, 32), 128, 0, stream>>>(Qb, Kb, Mq, Mk);
  attn_kernel<<<1024, 128, 0, stream>>>(Qb, Kb, VTb, alib, Mq, Mk, Yb);
  gemm_proj_kernel<<<dim3(64, 4), 256, 0, stream>>>(Yb, wprojT, bproj, out);
}

// Round 4
// 89.855 us; speedup vs baseline: 2.3046x; 1.1638x over previous
//
#include <hip/hip_runtime.h>
#include <hip/hip_bf16.h>

#define LOG2E 1.4426950408889634f

typedef __attribute__((ext_vector_type(8))) short short8;
typedef __attribute__((ext_vector_type(8))) __bf16 bf16x8;
typedef __attribute__((ext_vector_type(4))) float f32x4;

__device__ __forceinline__ unsigned short f2b(float f){
  unsigned int u = __builtin_bit_cast(unsigned int, f);
  u += 0x7fffu + ((u >> 16) & 1u);
  return (unsigned short)(u >> 16);
}

__device__ __forceinline__ float b2f(unsigned short s){
  unsigned int u = ((unsigned int)s) << 16;
  return __builtin_bit_cast(float, u);
}

__device__ __forceinline__ unsigned int cvtpk(float lo, float hi){
  unsigned int r;
  asm("v_cvt_pk_bf16_f32 %0, %1, %2" : "=v"(r) : "v"(lo), "v"(hi));
  return r;
}

__device__ __forceinline__ void gload16(const void* g, void* l){
  __builtin_amdgcn_global_load_lds(
      (const __attribute__((address_space(1))) unsigned int*)g,
      (__attribute__((address_space(3))) unsigned int*)l, 16, 0, 0);
}

// ---------------- conversion kernels ----------------
__global__ __launch_bounds__(256) void cvt_x_kernel(const float* __restrict__ in,
                                                    unsigned short* __restrict__ out){
  size_t i = ((size_t)blockIdx.x * 256 + threadIdx.x) * 8;
  float4 a = *(const float4*)(in + i);
  float4 b = *(const float4*)(in + i + 4);
  short8 s;
  s[0]=(short)f2b(a.x); s[1]=(short)f2b(a.y); s[2]=(short)f2b(a.z); s[3]=(short)f2b(a.w);
  s[4]=(short)f2b(b.x); s[5]=(short)f2b(b.y); s[6]=(short)f2b(b.z); s[7]=(short)f2b(b.w);
  *(short8*)(out + i) = s;
}

// Tiled transpose: out[c][r] = bf16(in[r][c]).  64x64 tiles, coalesced both sides.
__global__ __launch_bounds__(256) void cvt_tr_kernel(const float* __restrict__ in,
                                                     unsigned short* __restrict__ out,
                                                     int R, int C){
  __shared__ unsigned short T[64][72];
  const int tid = threadIdx.x;
  const int r0 = blockIdx.y * 64, c0 = blockIdx.x * 64;
  {
    const int i = tid >> 2, jg = (tid & 3) * 16;
    const float* src = in + (size_t)(r0 + i) * C + c0 + jg;
    #pragma unroll
    for (int e = 0; e < 16; e += 4){
      float4 v = *(const float4*)(src + e);
      T[i][jg + e + 0] = f2b(v.x);
      T[i][jg + e + 1] = f2b(v.y);
      T[i][jg + e + 2] = f2b(v.z);
      T[i][jg + e + 3] = f2b(v.w);
    }
  }
  __syncthreads();
  {
    const int j = tid >> 2, ig = (tid & 3) * 16;
    short8 w0, w1;
    #pragma unroll
    for (int e = 0; e < 8; e++) w0[e] = (short)T[ig + e][j];
    #pragma unroll
    for (int e = 0; e < 8; e++) w1[e] = (short)T[ig + 8 + e][j];
    unsigned short* dst = out + (size_t)(c0 + j) * R + r0 + ig;
    *(short8*)dst = w0;
    *(short8*)(dst + 8) = w1;
  }
}

// ---------------- QKV GEMM (BK=64, global_load_lds staging) ----------------
__global__ __launch_bounds__(256,2) void gemm_qkv_kernel(
    const unsigned short* __restrict__ A,
    const unsigned short* __restrict__ Bt,
    const float* __restrict__ bias,
    unsigned short* __restrict__ Qb,
    unsigned short* __restrict__ Kb,
    unsigned short* __restrict__ VTb){
  __shared__ unsigned short As[128*64];
  __shared__ unsigned short Bs[128*64];
  const int tid = threadIdx.x, wid = tid >> 6, lane = tid & 63;
  const int wr = wid >> 1, wc = wid & 1;
  const int fr = lane & 15, fq = lane >> 4;
  const int fr7 = fr & 7;
  const int bm = blockIdx.x * 128, bn = blockIdx.y * 128;
  f32x4 acc[4][4];
  #pragma unroll
  for (int m=0;m<4;m++)
    #pragma unroll
    for (int n=0;n<4;n++) acc[m][n] = (f32x4){0.f,0.f,0.f,0.f};

  for (int k0 = 0; k0 < 512; k0 += 64){
    __syncthreads();
    #pragma unroll
    for (int it=0; it<4; it++){
      const int s = it*256 + tid;
      const int row = s >> 3, c = s & 7;
      const int sc = c ^ (row & 7);
      void* al = (void*)(As + (it*256 + wid*64)*8);
      void* bl = (void*)(Bs + (it*256 + wid*64)*8);
      gload16(A  + (size_t)(bm + row)*512 + k0 + sc*8, al);
      gload16(Bt + (size_t)(bn + row)*512 + k0 + sc*8, bl);
    }
    __syncthreads();
    bf16x8 af[4][2], bfv[4][2];
    #pragma unroll
    for (int m=0;m<4;m++)
      #pragma unroll
      for (int kk=0;kk<2;kk++)
        af[m][kk]  = *(const bf16x8*)&As[(wr*64 + m*16 + fr)*64 + (((kk*4+fq)^fr7)*8)];
    #pragma unroll
    for (int n=0;n<4;n++)
      #pragma unroll
      for (int kk=0;kk<2;kk++)
        bfv[n][kk] = *(const bf16x8*)&Bs[(wc*64 + n*16 + fr)*64 + (((kk*4+fq)^fr7)*8)];
    #pragma unroll
    for (int kk=0;kk<2;kk++)
      #pragma unroll
      for (int m=0;m<4;m++)
        #pragma unroll
        for (int n=0;n<4;n++)
          acc[m][n] = __builtin_amdgcn_mfma_f32_16x16x32_bf16(af[m][kk], bfv[n][kk], acc[m][n], 0,0,0);
  }

  const float SCQ = 0.125f * LOG2E;
  #pragma unroll
  for (int m=0;m<4;m++){
    const int row0 = bm + wr*64 + m*16 + fq*4;
    const int b_ = row0 >> 11, t_ = row0 & 2047;
    #pragma unroll
    for (int n=0;n<4;n++){
      const int col = bn + wc*64 + n*16 + fr;
      const int which = col >> 9, c = col & 511, hh = c >> 6, dd = c & 63;
      const float bv = bias[col];
      if (which == 0){
        #pragma unroll
        for (int g=0; g<4; g++)
          Qb[((size_t)(b_*8 + hh)*2048 + t_ + g)*64 + dd] = f2b((acc[m][n][g] + bv)*SCQ);
      } else if (which == 1){
        #pragma unroll
        for (int g=0; g<4; g++)
          Kb[((size_t)(b_*8 + hh)*2048 + t_ + g)*64 + dd] = f2b(acc[m][n][g] + bv);
      } else {
        uint2 pk;
        pk.x = cvtpk(acc[m][n][0] + bv, acc[m][n][1] + bv);
        pk.y = cvtpk(acc[m][n][2] + bv, acc[m][n][3] + bv);
        *(uint2*)&VTb[((size_t)(b_*8 + hh)*64 + dd)*2048 + t_] = pk;
      }
    }
  }
}

// ---------------- norm prepass ----------------
__global__ __launch_bounds__(128) void norms_kernel(
    const unsigned short* __restrict__ Q,
    const unsigned short* __restrict__ K,
    float* __restrict__ Mq, float* __restrict__ Mk){
  __shared__ float red[2];
  const int ch = blockIdx.x, bh = blockIdx.y;
  const int tid = threadIdx.x, wid = tid >> 6;
  const int row = tid >> 1, half = (tid & 1) * 32;
  #pragma unroll
  for (int s = 0; s < 2; s++){
    const unsigned short* base = (s ? K : Q) + (size_t)bh * 131072 + (size_t)(ch*64 + row)*64 + half;
    float ss = 0.f;
    #pragma unroll
    for (int j=0;j<4;j++){
      short8 v = *(const short8*)(base + j*8);
      #pragma unroll
      for (int e=0;e<8;e++){
        float f = b2f((unsigned short)v[e]);
        ss = fmaf(f, f, ss);
      }
    }
    ss += __shfl_xor(ss, 1);
    float m = ss;
    #pragma unroll
    for (int d=2; d<64; d<<=1) m = fmaxf(m, __shfl_xor(m, d));
    if ((tid & 63) == 0) red[wid] = m;
    __syncthreads();
    if (tid == 0)
      (s ? Mk : Mq)[bh*32 + ch] = sqrtf(fmaxf(red[0], red[1]));
    __syncthreads();
  }
}

// ---------------- windowed flash attention (S^T formulation) ----------------
__global__ __launch_bounds__(128,2) void attn_kernel(
    const unsigned short* __restrict__ Q,
    const unsigned short* __restrict__ K,
    const unsigned short* __restrict__ VT,
    const float* __restrict__ alib,
    const float* __restrict__ Mqa,
    const float* __restrict__ Mka,
    unsigned short* __restrict__ Y){
  __shared__ unsigned short Ks[64*64];
  __shared__ unsigned short Vs[64*64];
  __shared__ unsigned short Ps[2][32][72];
  __shared__ float MkS[32];
  __shared__ float wred[2];
  const int tid = threadIdx.x, wid = tid >> 6, lane = tid & 63;
  const int fr = lane & 15, fq = lane >> 4;
  const int fr7 = fr & 7;
  const int id = blockIdx.x;
  const int h = id >> 7, r_ = id & 127, b = r_ >> 5, qc = r_ & 31;
  const int bh = b*8 + h;
  const int q0 = qc*64 + wid*32;
  const unsigned short* Qp = Q  + (size_t)bh * 131072;
  const unsigned short* Kp = K  + (size_t)bh * 131072;
  const unsigned short* Vp = VT + (size_t)bh * 131072;
  const float nmh2 = alib[(size_t)h * 4194304 + 1] * LOG2E;
  const float MqMk0 = Mqa[bh*32 + qc];
  if (tid < 32) MkS[tid] = Mka[bh*32 + tid];

  bf16x8 qf[2][2];
  #pragma unroll
  for (int mi=0;mi<2;mi++)
    #pragma unroll
    for (int kk=0;kk<2;kk++)
      qf[mi][kk] = *(const bf16x8*)(Qp + (size_t)(q0 + mi*16 + fr)*64 + kk*32 + fq*8);

  f32x4 o[2][4];
  #pragma unroll
  for (int mi=0;mi<2;mi++)
    #pragma unroll
    for (int ni=0;ni<4;ni++) o[mi][ni] = (f32x4){0.f,0.f,0.f,0.f};
  float mr[2] = {-1e30f, -1e30f}, lr[2] = {0.f, 0.f};
  const float qif[2] = {(float)(q0 + fr), (float)(q0 + 16 + fr)};

  auto process = [&](int kt){
    const int kb = kt * 64;
    __syncthreads();
    #pragma unroll
    for (int it=0; it<4; it++){
      const int s = it*128 + tid;
      const int row = s >> 3, c = s & 7;
      const int sc = c ^ (row & 7);
      void* kl = (void*)(Ks + (it*128 + wid*64)*8);
      void* vl = (void*)(Vs + (it*128 + wid*64)*8);
      gload16(Kp + (size_t)(kb + row)*64 + sc*8, kl);
      gload16(Vp + (size_t)row*2048 + kb + sc*8, vl);
    }
    __syncthreads();

    bf16x8 kf[4][2], vf[4][2];
    #pragma unroll
    for (int ni=0;ni<4;ni++)
      #pragma unroll
      for (int kk=0;kk<2;kk++){
        const int r = ni*16 + fr;
        const int sw = ((kk*4 + fq) ^ fr7) * 8;
        kf[ni][kk] = *(const bf16x8*)&Ks[r*64 + sw];
        vf[ni][kk] = *(const bf16x8*)&Vs[r*64 + sw];
      }

    f32x4 st[2][4];
    const f32x4 fz = {0.f,0.f,0.f,0.f};
    #pragma unroll
    for (int mi=0;mi<2;mi++)
      #pragma unroll
      for (int ni=0;ni<4;ni++){
        f32x4 t0 = __builtin_amdgcn_mfma_f32_16x16x32_bf16(kf[ni][0], qf[mi][0], fz, 0,0,0);
        st[mi][ni] = __builtin_amdgcn_mfma_f32_16x16x32_bf16(kf[ni][1], qf[mi][1], t0, 0,0,0);
      }

    #pragma unroll
    for (int mi=0;mi<2;mi++){
      const float base = qif[mi] - (float)(kb + fq*4);
      #pragma unroll
      for (int ni=0;ni<4;ni++)
        #pragma unroll
        for (int g=0;g<4;g++){
          const float d = fabsf(base - (float)(ni*16 + g));
          st[mi][ni][g] = fmaf(nmh2, d, st[mi][ni][g]);
        }
      float m0 = fmaxf(fmaxf(st[mi][0][0], st[mi][0][1]), fmaxf(st[mi][0][2], st[mi][0][3]));
      float m1 = fmaxf(fmaxf(st[mi][1][0], st[mi][1][1]), fmaxf(st[mi][1][2], st[mi][1][3]));
      float m2 = fmaxf(fmaxf(st[mi][2][0], st[mi][2][1]), fmaxf(st[mi][2][2], st[mi][2][3]));
      float m3 = fmaxf(fmaxf(st[mi][3][0], st[mi][3][1]), fmaxf(st[mi][3][2], st[mi][3][3]));
      float tm = fmaxf(fmaxf(m0, m1), fmaxf(m2, m3));
      tm = fmaxf(tm, __shfl_xor(tm, 16));
      tm = fmaxf(tm, __shfl_xor(tm, 32));

      const bool nog = __all(tm <= mr[mi]);
      float mn, sc;
      if (nog){
        mn = mr[mi];
      } else {
        mn = fmaxf(mr[mi], tm);
        sc = exp2f(mr[mi] - mn);
        mr[mi] = mn;
      }
      float rs = 0.f;
      #pragma unroll
      for (int ni=0;ni<4;ni++){
        #pragma unroll
        for (int g=0;g<4;g++){
          const float p = exp2f(st[mi][ni][g] - mn);
          st[mi][ni][g] = p;
          rs += p;
        }
      }
      rs += __shfl_xor(rs, 16);
      rs += __shfl_xor(rs, 32);
      if (nog){
        lr[mi] += rs;
      } else {
        lr[mi] = lr[mi]*sc + rs;
        #pragma unroll
        for (int g=0;g<4;g++){
          const float sv = __shfl(sc, fq*4 + g);
          #pragma unroll
          for (int ni=0;ni<4;ni++) o[mi][ni][g] *= sv;
        }
      }
      #pragma unroll
      for (int ni=0;ni<4;ni++){
        uint2 pk;
        pk.x = cvtpk(st[mi][ni][0], st[mi][ni][1]);
        pk.y = cvtpk(st[mi][ni][2], st[mi][ni][3]);
        *(uint2*)&Ps[wid][mi*16 + fr][ni*16 + fq*4] = pk;
      }
    }

    bf16x8 pf[2][2];
    #pragma unroll
    for (int mi=0;mi<2;mi++)
      #pragma unroll
      for (int kk=0;kk<2;kk++)
        pf[mi][kk] = *(const bf16x8*)&Ps[wid][mi*16 + fr][kk*32 + fq*8];
    #pragma unroll
    for (int mi=0;mi<2;mi++)
      #pragma unroll
      for (int ni=0;ni<4;ni++){
        o[mi][ni] = __builtin_amdgcn_mfma_f32_16x16x32_bf16(pf[mi][0], vf[ni][0], o[mi][ni], 0,0,0);
        o[mi][ni] = __builtin_amdgcn_mfma_f32_16x16x32_bf16(pf[mi][1], vf[ni][1], o[mi][ni], 0,0,0);
      }
  };

  auto refresh = [&](float* thr){
    float m = fminf(mr[0], mr[1]);
    #pragma unroll
    for (int d=1; d<16; d<<=1) m = fminf(m, __shfl_xor(m, d));
    if (lane == 0) wred[wid] = m;
    __syncthreads();
    *thr = fminf(wred[0], wred[1]) - 20.0f;
  };

  // diagonal tile first
  process(qc);
  float thresh;
  refresh(&thresh);
  float maxMk = 0.f;
  #pragma unroll
  for (int t=0; t<32; t++) maxMk = fmaxf(maxMk, MkS[t]);

  for (int dt = 1; dt < 32; dt++){
    const float dmin = (float)((dt - 1)*64 + 1);
    const float biasmax = nmh2 * dmin;
    if (MqMk0 * maxMk + biasmax < thresh) break;
    int kt = qc + dt;
    if (kt < 32 && MqMk0 * MkS[kt] + biasmax >= thresh) process(kt);
    kt = qc - dt;
    if (kt >= 0 && MqMk0 * MkS[kt] + biasmax >= thresh) process(kt);
    if (dt <= 2) refresh(&thresh);
  }

  #pragma unroll
  for (int mi=0;mi<2;mi++){
    const float inv = 1.0f / lr[mi];
    #pragma unroll
    for (int g=0;g<4;g++){
      const float iv = __shfl(inv, fq*4 + g);
      const int t = q0 + mi*16 + fq*4 + g;
      #pragma unroll
      for (int ni=0;ni<4;ni++)
        Y[(size_t)(b*2048 + t)*512 + h*64 + ni*16 + fr] = f2b(o[mi][ni][g] * iv);
    }
  }
}

// ---------------- output projection GEMM (BK=64, global_load_lds staging) ----------------
__global__ __launch_bounds__(256,2) void gemm_proj_kernel(
    const unsigned short* __restrict__ A,
    const unsigned short* __restrict__ Bt,
    const float* __restrict__ bias,
    float* __restrict__ out){
  __shared__ unsigned short As[128*64];
  __shared__ unsigned short Bs[128*64];
  const int tid = threadIdx.x, wid = tid >> 6, lane = tid & 63;
  const int wr = wid >> 1, wc = wid & 1;
  const int fr = lane & 15, fq = lane >> 4;
  const int fr7 = fr & 7;
  const int bm = blockIdx.x * 128, bn = blockIdx.y * 128;
  f32x4 acc[4][4];
  #pragma unroll
  for (int m=0;m<4;m++)
    #pragma unroll
    for (int n=0;n<4;n++) acc[m][n] = (f32x4){0.f,0.f,0.f,0.f};

  for (int k0 = 0; k0 < 512; k0 += 64){
    __syncthreads();
    #pragma unroll
    for (int it=0; it<4; it++){
      const int s = it*256 + tid;
      const int row = s >> 3, c = s & 7;
      const int sc = c ^ (row & 7);
      void* al = (void*)(As + (it*256 + wid*64)*8);
      void* bl = (void*)(Bs + (it*256 + wid*64)*8);
      gload16(A  + (size_t)(bm + row)*512 + k0 + sc*8, al);
      gload16(Bt + (size_t)(bn + row)*512 + k0 + sc*8, bl);
    }
    __syncthreads();
    bf16x8 af[4][2], bfv[4][2];
    #pragma unroll
    for (int m=0;m<4;m++)
      #pragma unroll
      for (int kk=0;kk<2;kk++)
        af[m][kk]  = *(const bf16x8*)&As[(wr*64 + m*16 + fr)*64 + (((kk*4+fq)^fr7)*8)];
    #pragma unroll
    for (int n=0;n<4;n++)
      #pragma unroll
      for (int kk=0;kk<2;kk++)
        bfv[n][kk] = *(const bf16x8*)&Bs[(wc*64 + n*16 + fr)*64 + (((kk*4+fq)^fr7)*8)];
    #pragma unroll
    for (int kk=0;kk<2;kk++)
      #pragma unroll
      for (int m=0;m<4;m++)
        #pragma unroll
        for (int n=0;n<4;n++)
          acc[m][n] = __builtin_amdgcn_mfma_f32_16x16x32_bf16(af[m][kk], bfv[n][kk], acc[m][n], 0,0,0);
  }

  #pragma unroll
  for (int m=0;m<4;m++){
    const int row0 = bm + wr*64 + m*16 + fq*4;
    #pragma unroll
    for (int n=0;n<4;n++){
      const int col = bn + wc*64 + n*16 + fr;
      const float bv = bias[col];
      #pragma unroll
      for (int g=0; g<4; g++)
        out[(size_t)(row0 + g)*512 + col] = acc[m][n][g] + bv;
    }
  }
}

// ---------------- launch ----------------
extern "C" void kernel_launch(void* const* d_in, const int* in_sizes, int n_in,
                              void* d_out, int out_size, void* d_ws, size_t ws_size,
                              hipStream_t stream){
  const float* x     = (const float*)d_in[0];
  const float* Wqkv  = (const float*)d_in[1];
  const float* bqkv  = (const float*)d_in[2];
  const float* Wproj = (const float*)d_in[3];
  const float* bproj = (const float*)d_in[4];
  const float* alib  = (const float*)d_in[5];
  char* ws = (char*)d_ws;
  unsigned short* xb     = (unsigned short*)(ws);
  unsigned short* wqkvT  = (unsigned short*)(ws + 8388608);
  unsigned short* wprojT = (unsigned short*)(ws + 9961472);
  unsigned short* Qb     = (unsigned short*)(ws + 10485760);
  unsigned short* Kb     = (unsigned short*)(ws + 18874368);
  unsigned short* VTb    = (unsigned short*)(ws + 27262976);
  unsigned short* Yb     = (unsigned short*)(ws + 35651584);
  float* out = (float*)d_out;
  float* Mq = out + 4194304 - 2048;
  float* Mk = Mq + 1024;

  cvt_x_kernel<<<2048, 256, 0, stream>>>(x, xb);
  cvt_tr_kernel<<<dim3(24, 8), 256, 0, stream>>>(Wqkv, wqkvT, 512, 1536);
  cvt_tr_kernel<<<dim3(8, 8), 256, 0, stream>>>(Wproj, wprojT, 512, 512);
  gemm_qkv_kernel<<<dim3(64, 12), 256, 0, stream>>>(xb, wqkvT, bqkv, Qb, Kb, VTb);
  norms_kernel<<<dim3(32, 32), 128, 0, stream>>>(Qb, Kb, Mq, Mk);
  attn_kernel<<<1024, 128, 0, stream>>>(Qb, Kb, VTb, alib, Mq, Mk, Yb);
  gemm_proj_kernel<<<dim3(64, 4), 256, 0, stream>>>(Yb, wprojT, bproj, out);
}

// Round 5
// 80.368 us; speedup vs baseline: 2.5766x; 1.1180x over previous
//
#include <hip/hip_runtime.h>
#include <hip/hip_bf16.h>

#define LOG2E 1.4426950408889634f

typedef __attribute__((ext_vector_type(8))) short short8;
typedef __attribute__((ext_vector_type(8))) __bf16 bf16x8;
typedef __attribute__((ext_vector_type(4))) float f32x4;

__device__ __forceinline__ unsigned short f2b(float f){
  unsigned int u = __builtin_bit_cast(unsigned int, f);
  u += 0x7fffu + ((u >> 16) & 1u);
  return (unsigned short)(u >> 16);
}

__device__ __forceinline__ unsigned int cvtpk(float lo, float hi){
  unsigned int r;
  asm("v_cvt_pk_bf16_f32 %0, %1, %2" : "=v"(r) : "v"(lo), "v"(hi));
  return r;
}

__device__ __forceinline__ void gload16(const void* g, void* l){
  __builtin_amdgcn_global_load_lds(
      (const __attribute__((address_space(1))) unsigned int*)g,
      (__attribute__((address_space(3))) unsigned int*)l, 16, 0, 0);
}

// ---------------- merged prep kernel: x->bf16, Wqkv^T, Wproj^T ----------------
__global__ __launch_bounds__(256) void prep_kernel(
    const float* __restrict__ x, const float* __restrict__ Wqkv, const float* __restrict__ Wproj,
    unsigned short* __restrict__ xb, unsigned short* __restrict__ wqkvT, unsigned short* __restrict__ wprojT){
  __shared__ unsigned short T[64][72];
  const int bid = blockIdx.x, tid = threadIdx.x;
  if (bid < 2048){
    size_t i = ((size_t)bid * 256 + tid) * 8;
    float4 a = *(const float4*)(x + i);
    float4 b = *(const float4*)(x + i + 4);
    short8 s;
    s[0]=(short)f2b(a.x); s[1]=(short)f2b(a.y); s[2]=(short)f2b(a.z); s[3]=(short)f2b(a.w);
    s[4]=(short)f2b(b.x); s[5]=(short)f2b(b.y); s[6]=(short)f2b(b.z); s[7]=(short)f2b(b.w);
    *(short8*)(xb + i) = s;
    return;
  }
  const float* in; unsigned short* out; int R, C, bx, by;
  if (bid < 2240){ int t = bid - 2048; bx = t % 24; by = t / 24; in = Wqkv; out = wqkvT; R = 512; C = 1536; }
  else           { int t = bid - 2240; bx = t % 8;  by = t / 8;  in = Wproj; out = wprojT; R = 512; C = 512; }
  const int r0 = by * 64, c0 = bx * 64;
  {
    const int i = tid >> 2, jg = (tid & 3) * 16;
    const float* src = in + (size_t)(r0 + i) * C + c0 + jg;
    #pragma unroll
    for (int e = 0; e < 16; e += 4){
      float4 v = *(const float4*)(src + e);
      T[i][jg + e + 0] = f2b(v.x);
      T[i][jg + e + 1] = f2b(v.y);
      T[i][jg + e + 2] = f2b(v.z);
      T[i][jg + e + 3] = f2b(v.w);
    }
  }
  __syncthreads();
  {
    const int j = tid >> 2, ig = (tid & 3) * 16;
    short8 w0, w1;
    #pragma unroll
    for (int e = 0; e < 8; e++) w0[e] = (short)T[ig + e][j];
    #pragma unroll
    for (int e = 0; e < 8; e++) w1[e] = (short)T[ig + 8 + e][j];
    unsigned short* dst = out + (size_t)(c0 + j) * R + r0 + ig;
    *(short8*)dst = w0;
    *(short8*)(dst + 8) = w1;
  }
}

// ---------------- QKV GEMM (BK=64, global_load_lds) + fused norm epilogue ----------------
__global__ __launch_bounds__(256,2) void gemm_qkv_kernel(
    const unsigned short* __restrict__ A,
    const unsigned short* __restrict__ Bt,
    const float* __restrict__ bias,
    unsigned short* __restrict__ Qb,
    unsigned short* __restrict__ Kb,
    unsigned short* __restrict__ VTb,
    float* __restrict__ Mq, float* __restrict__ Mk){
  __shared__ unsigned short As[128*64];
  __shared__ unsigned short Bs[128*64];
  const int tid = threadIdx.x, wid = tid >> 6, lane = tid & 63;
  const int wr = wid >> 1, wc = wid & 1;
  const int fr = lane & 15, fq = lane >> 4;
  const int fr7 = fr & 7;
  const int bm = blockIdx.x * 128, bn = blockIdx.y * 128;
  f32x4 acc[4][4];
  #pragma unroll
  for (int m=0;m<4;m++)
    #pragma unroll
    for (int n=0;n<4;n++) acc[m][n] = (f32x4){0.f,0.f,0.f,0.f};

  for (int k0 = 0; k0 < 512; k0 += 64){
    __syncthreads();
    #pragma unroll
    for (int it=0; it<4; it++){
      const int s = it*256 + tid;
      const int row = s >> 3, c = s & 7;
      const int sc = c ^ (row & 7);
      void* al = (void*)(As + (it*256 + wid*64)*8);
      void* bl = (void*)(Bs + (it*256 + wid*64)*8);
      gload16(A  + (size_t)(bm + row)*512 + k0 + sc*8, al);
      gload16(Bt + (size_t)(bn + row)*512 + k0 + sc*8, bl);
    }
    __syncthreads();
    bf16x8 af[4][2], bfv[4][2];
    #pragma unroll
    for (int m=0;m<4;m++)
      #pragma unroll
      for (int kk=0;kk<2;kk++)
        af[m][kk]  = *(const bf16x8*)&As[(wr*64 + m*16 + fr)*64 + (((kk*4+fq)^fr7)*8)];
    #pragma unroll
    for (int n=0;n<4;n++)
      #pragma unroll
      for (int kk=0;kk<2;kk++)
        bfv[n][kk] = *(const bf16x8*)&Bs[(wc*64 + n*16 + fr)*64 + (((kk*4+fq)^fr7)*8)];
    #pragma unroll
    for (int kk=0;kk<2;kk++)
      #pragma unroll
      for (int m=0;m<4;m++)
        #pragma unroll
        for (int n=0;n<4;n++)
          acc[m][n] = __builtin_amdgcn_mfma_f32_16x16x32_bf16(af[m][kk], bfv[n][kk], acc[m][n], 0,0,0);
  }

  const float SCQ = 0.125f * LOG2E;
  const int colbase = bn + wc*64;
  const int which = colbase >> 9;
  float ss[4][4];
  #pragma unroll
  for (int m=0;m<4;m++)
    #pragma unroll
    for (int g=0;g<4;g++) ss[m][g] = 0.f;

  #pragma unroll
  for (int m=0;m<4;m++){
    const int row0 = bm + wr*64 + m*16 + fq*4;
    const int b_ = row0 >> 11, t_ = row0 & 2047;
    #pragma unroll
    for (int n=0;n<4;n++){
      const int col = colbase + n*16 + fr;
      const int c = col & 511, hh = c >> 6, dd = c & 63;
      const float bv = bias[col];
      if (which == 0){
        #pragma unroll
        for (int g=0; g<4; g++){
          const float v = (acc[m][n][g] + bv) * SCQ;
          ss[m][g] = fmaf(v, v, ss[m][g]);
          Qb[((size_t)(b_*8 + hh)*2048 + t_ + g)*64 + dd] = f2b(v);
        }
      } else if (which == 1){
        #pragma unroll
        for (int g=0; g<4; g++){
          const float v = acc[m][n][g] + bv;
          ss[m][g] = fmaf(v, v, ss[m][g]);
          Kb[((size_t)(b_*8 + hh)*2048 + t_ + g)*64 + dd] = f2b(v);
        }
      } else {
        uint2 pk;
        pk.x = cvtpk(acc[m][n][0] + bv, acc[m][n][1] + bv);
        pk.y = cvtpk(acc[m][n][2] + bv, acc[m][n][3] + bv);
        *(uint2*)&VTb[((size_t)(b_*8 + hh)*64 + dd)*2048 + t_] = pk;
      }
    }
  }

  if (which <= 1){
    #pragma unroll
    for (int m=0;m<4;m++)
      #pragma unroll
      for (int g=0;g<4;g++){
        float s = ss[m][g];
        s += __shfl_xor(s, 1); s += __shfl_xor(s, 2);
        s += __shfl_xor(s, 4); s += __shfl_xor(s, 8);
        ss[m][g] = s;
      }
    float mx = 0.f;
    #pragma unroll
    for (int m=0;m<4;m++)
      #pragma unroll
      for (int g=0;g<4;g++) mx = fmaxf(mx, ss[m][g]);
    mx = fmaxf(mx, __shfl_xor(mx, 16));
    mx = fmaxf(mx, __shfl_xor(mx, 32));
    if (lane == 0){
      const int rowbase = bm + wr*64;
      const int b_ = rowbase >> 11, qc_ = (rowbase >> 6) & 31;
      const int h_ = (colbase >> 6) & 7;
      float* M = which ? Mk : Mq;
      M[(b_*8 + h_)*32 + qc_] = sqrtf(mx) * 1.01f;
    }
  }
}

// ---------------- windowed flash attention, pipelined (S^T formulation) ----------------
__global__ __launch_bounds__(128,2) void attn_kernel(
    const unsigned short* __restrict__ Q,
    const unsigned short* __restrict__ K,
    const unsigned short* __restrict__ VT,
    const float* __restrict__ alib,
    const float* __restrict__ Mqa,
    const float* __restrict__ Mka,
    unsigned short* __restrict__ Y){
  __shared__ unsigned short Ks[2][64*64];
  __shared__ unsigned short Vs[2][64*64];
  __shared__ unsigned short Ps[2][32][72];
  __shared__ float MkS[32];
  __shared__ float wred[2];
  __shared__ int lst[32];
  __shared__ int nsh;
  const int tid = threadIdx.x, wid = tid >> 6, lane = tid & 63;
  const int fr = lane & 15, fq = lane >> 4;
  const int fr7 = fr & 7;
  const int id = blockIdx.x;
  const int h = id >> 7, r_ = id & 127, b = r_ >> 5, qc = r_ & 31;
  const int bh = b*8 + h;
  const int q0 = qc*64 + wid*32;
  const unsigned short* Qp = Q  + (size_t)bh * 131072;
  const unsigned short* Kp = K  + (size_t)bh * 131072;
  const unsigned short* Vp = VT + (size_t)bh * 131072;
  const float nmh2 = alib[(size_t)h * 4194304 + 1] * LOG2E;
  const float MqMk0 = Mqa[bh*32 + qc];
  if (tid < 32) MkS[tid] = Mka[bh*32 + tid];

  bf16x8 qf[2][2];
  #pragma unroll
  for (int mi=0;mi<2;mi++)
    #pragma unroll
    for (int kk=0;kk<2;kk++)
      qf[mi][kk] = *(const bf16x8*)(Qp + (size_t)(q0 + mi*16 + fr)*64 + kk*32 + fq*8);

  f32x4 o[2][4];
  #pragma unroll
  for (int mi=0;mi<2;mi++)
    #pragma unroll
    for (int ni=0;ni<4;ni++) o[mi][ni] = (f32x4){0.f,0.f,0.f,0.f};
  float mr[2] = {-1e30f, -1e30f}, lr[2] = {0.f, 0.f};
  const float qif[2] = {(float)(q0 + fr), (float)(q0 + 16 + fr)};

  auto stage = [&](int kt, int buf){
    const int kb = kt * 64;
    #pragma unroll
    for (int it=0; it<4; it++){
      const int s = it*128 + tid;
      const int row = s >> 3, c = s & 7;
      const int sc = c ^ (row & 7);
      gload16(Kp + (size_t)(kb + row)*64 + sc*8, (void*)(Ks[buf] + (it*128 + wid*64)*8));
      gload16(Vp + (size_t)row*2048 + kb + sc*8, (void*)(Vs[buf] + (it*128 + wid*64)*8));
    }
  };

  auto compute = [&](int kt, int buf){
    const int kb = kt * 64;
    const unsigned short* KsB = Ks[buf];
    const unsigned short* VsB = Vs[buf];
    bf16x8 kf[4][2], vf[4][2];
    #pragma unroll
    for (int ni=0;ni<4;ni++)
      #pragma unroll
      for (int kk=0;kk<2;kk++){
        const int r = ni*16 + fr;
        const int sw = ((kk*4 + fq) ^ fr7) * 8;
        kf[ni][kk] = *(const bf16x8*)&KsB[r*64 + sw];
        vf[ni][kk] = *(const bf16x8*)&VsB[r*64 + sw];
      }

    f32x4 st[2][4];
    const f32x4 fz = {0.f,0.f,0.f,0.f};
    #pragma unroll
    for (int mi=0;mi<2;mi++)
      #pragma unroll
      for (int ni=0;ni<4;ni++){
        f32x4 t0 = __builtin_amdgcn_mfma_f32_16x16x32_bf16(kf[ni][0], qf[mi][0], fz, 0,0,0);
        st[mi][ni] = __builtin_amdgcn_mfma_f32_16x16x32_bf16(kf[ni][1], qf[mi][1], t0, 0,0,0);
      }

    #pragma unroll
    for (int mi=0;mi<2;mi++){
      const float base = qif[mi] - (float)(kb + fq*4);
      #pragma unroll
      for (int ni=0;ni<4;ni++)
        #pragma unroll
        for (int g=0;g<4;g++){
          const float d = fabsf(base - (float)(ni*16 + g));
          st[mi][ni][g] = fmaf(nmh2, d, st[mi][ni][g]);
        }
      float m0 = fmaxf(fmaxf(st[mi][0][0], st[mi][0][1]), fmaxf(st[mi][0][2], st[mi][0][3]));
      float m1 = fmaxf(fmaxf(st[mi][1][0], st[mi][1][1]), fmaxf(st[mi][1][2], st[mi][1][3]));
      float m2 = fmaxf(fmaxf(st[mi][2][0], st[mi][2][1]), fmaxf(st[mi][2][2], st[mi][2][3]));
      float m3 = fmaxf(fmaxf(st[mi][3][0], st[mi][3][1]), fmaxf(st[mi][3][2], st[mi][3][3]));
      float tm = fmaxf(fmaxf(m0, m1), fmaxf(m2, m3));
      tm = fmaxf(tm, __shfl_xor(tm, 16));
      tm = fmaxf(tm, __shfl_xor(tm, 32));

      const bool nog = __all(tm <= mr[mi]);
      float mn, sc;
      if (nog){
        mn = mr[mi];
      } else {
        mn = fmaxf(mr[mi], tm);
        sc = exp2f(mr[mi] - mn);
        mr[mi] = mn;
      }
      float rs = 0.f;
      #pragma unroll
      for (int ni=0;ni<4;ni++){
        #pragma unroll
        for (int g=0;g<4;g++){
          const float p = exp2f(st[mi][ni][g] - mn);
          st[mi][ni][g] = p;
          rs += p;
        }
      }
      rs += __shfl_xor(rs, 16);
      rs += __shfl_xor(rs, 32);
      if (nog){
        lr[mi] += rs;
      } else {
        lr[mi] = lr[mi]*sc + rs;
        #pragma unroll
        for (int g=0;g<4;g++){
          const float sv = __shfl(sc, fq*4 + g);
          #pragma unroll
          for (int ni=0;ni<4;ni++) o[mi][ni][g] *= sv;
        }
      }
      #pragma unroll
      for (int ni=0;ni<4;ni++){
        uint2 pk;
        pk.x = cvtpk(st[mi][ni][0], st[mi][ni][1]);
        pk.y = cvtpk(st[mi][ni][2], st[mi][ni][3]);
        *(uint2*)&Ps[wid][mi*16 + fr][ni*16 + fq*4] = pk;
      }
    }

    bf16x8 pf[2][2];
    #pragma unroll
    for (int mi=0;mi<2;mi++)
      #pragma unroll
      for (int kk=0;kk<2;kk++)
        pf[mi][kk] = *(const bf16x8*)&Ps[wid][mi*16 + fr][kk*32 + fq*8];
    #pragma unroll
    for (int mi=0;mi<2;mi++)
      #pragma unroll
      for (int ni=0;ni<4;ni++){
        o[mi][ni] = __builtin_amdgcn_mfma_f32_16x16x32_bf16(pf[mi][0], vf[ni][0], o[mi][ni], 0,0,0);
        o[mi][ni] = __builtin_amdgcn_mfma_f32_16x16x32_bf16(pf[mi][1], vf[ni][1], o[mi][ni], 0,0,0);
      }
  };

  // ---- diagonal tile (serial) ----
  stage(qc, 0);
  asm volatile("s_waitcnt vmcnt(0)" ::: "memory");
  __builtin_amdgcn_sched_barrier(0);
  __builtin_amdgcn_s_barrier();
  compute(qc, 0);

  // ---- threshold ----
  {
    float m = fminf(mr[0], mr[1]);
    #pragma unroll
    for (int d=1; d<16; d<<=1) m = fminf(m, __shfl_xor(m, d));
    if (lane == 0) wred[wid] = m;
  }
  __syncthreads();
  const float thresh = fminf(wred[0], wred[1]) - 16.0f;

  // ---- build tile list (block-uniform) ----
  if (tid == 0){
    float maxMk = 0.f;
    #pragma unroll
    for (int t=0; t<32; t++) maxMk = fmaxf(maxMk, MkS[t]);
    int n = 0;
    for (int dt = 1; dt < 32; dt++){
      const float biasmax = nmh2 * (float)((dt - 1)*64 + 1);
      if (MqMk0 * maxMk + biasmax < thresh) break;
      int kt = qc + dt;
      if (kt < 32 && MqMk0 * MkS[kt] + biasmax >= thresh) lst[n++] = kt;
      kt = qc - dt;
      if (kt >= 0 && MqMk0 * MkS[kt] + biasmax >= thresh) lst[n++] = kt;
    }
    nsh = n;
  }
  __syncthreads();
  const int n = nsh;

  // ---- pipelined loop: tile j lives in buffer (j+1)&1 ----
  if (n > 0){
    stage(lst[0], 1);
    for (int j = 0; j < n; j++){
      asm volatile("s_waitcnt lgkmcnt(0)" ::: "memory");
      __builtin_amdgcn_sched_barrier(0);
      __builtin_amdgcn_s_barrier();            // safe to overwrite buf j&1
      if (j + 1 < n){
        stage(lst[j+1], j & 1);
        asm volatile("s_waitcnt vmcnt(8)" ::: "memory");
      } else {
        asm volatile("s_waitcnt vmcnt(0)" ::: "memory");
      }
      __builtin_amdgcn_sched_barrier(0);
      __builtin_amdgcn_s_barrier();            // buf (j+1)&1 staged for all waves
      compute(lst[j], (j+1)&1);
    }
  }

  // ---- epilogue ----
  #pragma unroll
  for (int mi=0;mi<2;mi++){
    const float inv = 1.0f / lr[mi];
    #pragma unroll
    for (int g=0;g<4;g++){
      const float iv = __shfl(inv, fq*4 + g);
      const int t = q0 + mi*16 + fq*4 + g;
      #pragma unroll
      for (int ni=0;ni<4;ni++)
        Y[(size_t)(b*2048 + t)*512 + h*64 + ni*16 + fr] = f2b(o[mi][ni][g] * iv);
    }
  }
}

// ---------------- output projection GEMM (BK=64, global_load_lds) ----------------
__global__ __launch_bounds__(256,2) void gemm_proj_kernel(
    const unsigned short* __restrict__ A,
    const unsigned short* __restrict__ Bt,
    const float* __restrict__ bias,
    float* __restrict__ out){
  __shared__ unsigned short As[128*64];
  __shared__ unsigned short Bs[128*64];
  const int tid = threadIdx.x, wid = tid >> 6, lane = tid & 63;
  const int wr = wid >> 1, wc = wid & 1;
  const int fr = lane & 15, fq = lane >> 4;
  const int fr7 = fr & 7;
  const int bm = blockIdx.x * 128, bn = blockIdx.y * 128;
  f32x4 acc[4][4];
  #pragma unroll
  for (int m=0;m<4;m++)
    #pragma unroll
    for (int n=0;n<4;n++) acc[m][n] = (f32x4){0.f,0.f,0.f,0.f};

  for (int k0 = 0; k0 < 512; k0 += 64){
    __syncthreads();
    #pragma unroll
    for (int it=0; it<4; it++){
      const int s = it*256 + tid;
      const int row = s >> 3, c = s & 7;
      const int sc = c ^ (row & 7);
      void* al = (void*)(As + (it*256 + wid*64)*8);
      void* bl = (void*)(Bs + (it*256 + wid*64)*8);
      gload16(A  + (size_t)(bm + row)*512 + k0 + sc*8, al);
      gload16(Bt + (size_t)(bn + row)*512 + k0 + sc*8, bl);
    }
    __syncthreads();
    bf16x8 af[4][2], bfv[4][2];
    #pragma unroll
    for (int m=0;m<4;m++)
      #pragma unroll
      for (int kk=0;kk<2;kk++)
        af[m][kk]  = *(const bf16x8*)&As[(wr*64 + m*16 + fr)*64 + (((kk*4+fq)^fr7)*8)];
    #pragma unroll
    for (int n=0;n<4;n++)
      #pragma unroll
      for (int kk=0;kk<2;kk++)
        bfv[n][kk] = *(const bf16x8*)&Bs[(wc*64 + n*16 + fr)*64 + (((kk*4+fq)^fr7)*8)];
    #pragma unroll
    for (int kk=0;kk<2;kk++)
      #pragma unroll
      for (int m=0;m<4;m++)
        #pragma unroll
        for (int n=0;n<4;n++)
          acc[m][n] = __builtin_amdgcn_mfma_f32_16x16x32_bf16(af[m][kk], bfv[n][kk], acc[m][n], 0,0,0);
  }

  #pragma unroll
  for (int m=0;m<4;m++){
    const int row0 = bm + wr*64 + m*16 + fq*4;
    #pragma unroll
    for (int n=0;n<4;n++){
      const int col = bn + wc*64 + n*16 + fr;
      const float bv = bias[col];
      #pragma unroll
      for (int g=0; g<4; g++)
        out[(size_t)(row0 + g)*512 + col] = acc[m][n][g] + bv;
    }
  }
}

// ---------------- launch ----------------
extern "C" void kernel_launch(void* const* d_in, const int* in_sizes, int n_in,
                              void* d_out, int out_size, void* d_ws, size_t ws_size,
                              hipStream_t stream){
  const float* x     = (const float*)d_in[0];
  const float* Wqkv  = (const float*)d_in[1];
  const float* bqkv  = (const float*)d_in[2];
  const float* Wproj = (const float*)d_in[3];
  const float* bproj = (const float*)d_in[4];
  const float* alib  = (const float*)d_in[5];
  char* ws = (char*)d_ws;
  unsigned short* xb     = (unsigned short*)(ws);
  unsigned short* wqkvT  = (unsigned short*)(ws + 8388608);
  unsigned short* wprojT = (unsigned short*)(ws + 9961472);
  unsigned short* Qb     = (unsigned short*)(ws + 10485760);
  unsigned short* Kb     = (unsigned short*)(ws + 18874368);
  unsigned short* VTb    = (unsigned short*)(ws + 27262976);
  unsigned short* Yb     = (unsigned short*)(ws + 35651584);
  float* out = (float*)d_out;
  float* Mq = out + 4194304 - 2048;
  float* Mk = Mq + 1024;

  prep_kernel<<<2304, 256, 0, stream>>>(x, Wqkv, Wproj, xb, wqkvT, wprojT);
  gemm_qkv_kernel<<<dim3(64, 12), 256, 0, stream>>>(xb, wqkvT, bqkv, Qb, Kb, VTb, Mq, Mk);
  attn_kernel<<<1024, 128, 0, stream>>>(Qb, Kb, VTb, alib, Mq, Mk, Yb);
  gemm_proj_kernel<<<dim3(64, 4), 256, 0, stream>>>(Yb, wprojT, bproj, out);
}

// Round 6
// 70.898 us; speedup vs baseline: 2.9208x; 1.1336x over previous
//
#include <hip/hip_runtime.h>
#include <hip/hip_bf16.h>

#define LOG2E 1.4426950408889634f

typedef __attribute__((ext_vector_type(8))) short short8;
typedef __attribute__((ext_vector_type(8))) __bf16 bf16x8;
typedef __attribute__((ext_vector_type(4))) float f32x4;

__device__ __forceinline__ unsigned short f2b(float f){
  unsigned int u = __builtin_bit_cast(unsigned int, f);
  u += 0x7fffu + ((u >> 16) & 1u);
  return (unsigned short)(u >> 16);
}

__device__ __forceinline__ unsigned int cvtpk(float lo, float hi){
  unsigned int r;
  asm("v_cvt_pk_bf16_f32 %0, %1, %2" : "=v"(r) : "v"(lo), "v"(hi));
  return r;
}

__device__ __forceinline__ void gload16(const void* g, void* l){
  __builtin_amdgcn_global_load_lds(
      (const __attribute__((address_space(1))) unsigned int*)g,
      (__attribute__((address_space(3))) unsigned int*)l, 16, 0, 0);
}

// ---------------- merged prep kernel: x->bf16, Wqkv^T, Wproj^T ----------------
__global__ __launch_bounds__(256) void prep_kernel(
    const float* __restrict__ x, const float* __restrict__ Wqkv, const float* __restrict__ Wproj,
    unsigned short* __restrict__ xb, unsigned short* __restrict__ wqkvT, unsigned short* __restrict__ wprojT){
  __shared__ unsigned short T[64][72];
  const int bid = blockIdx.x, tid = threadIdx.x;
  if (bid < 2048){
    size_t i = ((size_t)bid * 256 + tid) * 8;
    float4 a = *(const float4*)(x + i);
    float4 b = *(const float4*)(x + i + 4);
    short8 s;
    s[0]=(short)f2b(a.x); s[1]=(short)f2b(a.y); s[2]=(short)f2b(a.z); s[3]=(short)f2b(a.w);
    s[4]=(short)f2b(b.x); s[5]=(short)f2b(b.y); s[6]=(short)f2b(b.z); s[7]=(short)f2b(b.w);
    *(short8*)(xb + i) = s;
    return;
  }
  const float* in; unsigned short* out; int R, C, bx, by;
  if (bid < 2240){ int t = bid - 2048; bx = t % 24; by = t / 24; in = Wqkv; out = wqkvT; R = 512; C = 1536; }
  else           { int t = bid - 2240; bx = t % 8;  by = t / 8;  in = Wproj; out = wprojT; R = 512; C = 512; }
  const int r0 = by * 64, c0 = bx * 64;
  {
    const int i = tid >> 2, jg = (tid & 3) * 16;
    const float* src = in + (size_t)(r0 + i) * C + c0 + jg;
    #pragma unroll
    for (int e = 0; e < 16; e += 4){
      float4 v = *(const float4*)(src + e);
      T[i][jg + e + 0] = f2b(v.x);
      T[i][jg + e + 1] = f2b(v.y);
      T[i][jg + e + 2] = f2b(v.z);
      T[i][jg + e + 3] = f2b(v.w);
    }
  }
  __syncthreads();
  {
    const int j = tid >> 2, ig = (tid & 3) * 16;
    short8 w0, w1;
    #pragma unroll
    for (int e = 0; e < 8; e++) w0[e] = (short)T[ig + e][j];
    #pragma unroll
    for (int e = 0; e < 8; e++) w1[e] = (short)T[ig + 8 + e][j];
    unsigned short* dst = out + (size_t)(c0 + j) * R + r0 + ig;
    *(short8*)dst = w0;
    *(short8*)(dst + 8) = w1;
  }
}

// ---------------- QKV GEMM (BK=64, global_load_lds) + fused norm epilogue ----------------
__global__ __launch_bounds__(256,2) void gemm_qkv_kernel(
    const unsigned short* __restrict__ A,
    const unsigned short* __restrict__ Bt,
    const float* __restrict__ bias,
    unsigned short* __restrict__ Qb,
    unsigned short* __restrict__ Kb,
    unsigned short* __restrict__ VTb,
    float* __restrict__ Mq, float* __restrict__ Mk){
  __shared__ unsigned short As[128*64];
  __shared__ unsigned short Bs[128*64];
  const int tid = threadIdx.x, wid = tid >> 6, lane = tid & 63;
  const int wr = wid >> 1, wc = wid & 1;
  const int fr = lane & 15, fq = lane >> 4;
  const int fr7 = fr & 7;
  const int bm = blockIdx.x * 128, bn = blockIdx.y * 128;
  f32x4 acc[4][4];
  #pragma unroll
  for (int m=0;m<4;m++)
    #pragma unroll
    for (int n=0;n<4;n++) acc[m][n] = (f32x4){0.f,0.f,0.f,0.f};

  for (int k0 = 0; k0 < 512; k0 += 64){
    __syncthreads();
    #pragma unroll
    for (int it=0; it<4; it++){
      const int s = it*256 + tid;
      const int row = s >> 3, c = s & 7;
      const int sc = c ^ (row & 7);
      void* al = (void*)(As + (it*256 + wid*64)*8);
      void* bl = (void*)(Bs + (it*256 + wid*64)*8);
      gload16(A  + (size_t)(bm + row)*512 + k0 + sc*8, al);
      gload16(Bt + (size_t)(bn + row)*512 + k0 + sc*8, bl);
    }
    __syncthreads();
    bf16x8 af[4][2], bfv[4][2];
    #pragma unroll
    for (int m=0;m<4;m++)
      #pragma unroll
      for (int kk=0;kk<2;kk++)
        af[m][kk]  = *(const bf16x8*)&As[(wr*64 + m*16 + fr)*64 + (((kk*4+fq)^fr7)*8)];
    #pragma unroll
    for (int n=0;n<4;n++)
      #pragma unroll
      for (int kk=0;kk<2;kk++)
        bfv[n][kk] = *(const bf16x8*)&Bs[(wc*64 + n*16 + fr)*64 + (((kk*4+fq)^fr7)*8)];
    #pragma unroll
    for (int kk=0;kk<2;kk++)
      #pragma unroll
      for (int m=0;m<4;m++)
        #pragma unroll
        for (int n=0;n<4;n++)
          acc[m][n] = __builtin_amdgcn_mfma_f32_16x16x32_bf16(af[m][kk], bfv[n][kk], acc[m][n], 0,0,0);
  }

  const float SCQ = 0.125f * LOG2E;
  const int colbase = bn + wc*64;
  const int which = colbase >> 9;
  float ss[4][4];
  #pragma unroll
  for (int m=0;m<4;m++)
    #pragma unroll
    for (int g=0;g<4;g++) ss[m][g] = 0.f;

  #pragma unroll
  for (int m=0;m<4;m++){
    const int row0 = bm + wr*64 + m*16 + fq*4;
    const int b_ = row0 >> 11, t_ = row0 & 2047;
    #pragma unroll
    for (int n=0;n<4;n++){
      const int col = colbase + n*16 + fr;
      const int c = col & 511, hh = c >> 6, dd = c & 63;
      const float bv = bias[col];
      if (which == 0){
        #pragma unroll
        for (int g=0; g<4; g++){
          const float v = (acc[m][n][g] + bv) * SCQ;
          ss[m][g] = fmaf(v, v, ss[m][g]);
          Qb[((size_t)(b_*8 + hh)*2048 + t_ + g)*64 + dd] = f2b(v);
        }
      } else if (which == 1){
        #pragma unroll
        for (int g=0; g<4; g++){
          const float v = acc[m][n][g] + bv;
          ss[m][g] = fmaf(v, v, ss[m][g]);
          Kb[((size_t)(b_*8 + hh)*2048 + t_ + g)*64 + dd] = f2b(v);
        }
      } else {
        uint2 pk;
        pk.x = cvtpk(acc[m][n][0] + bv, acc[m][n][1] + bv);
        pk.y = cvtpk(acc[m][n][2] + bv, acc[m][n][3] + bv);
        *(uint2*)&VTb[((size_t)(b_*8 + hh)*64 + dd)*2048 + t_] = pk;
      }
    }
  }

  if (which <= 1){
    #pragma unroll
    for (int m=0;m<4;m++)
      #pragma unroll
      for (int g=0;g<4;g++){
        float s = ss[m][g];
        s += __shfl_xor(s, 1); s += __shfl_xor(s, 2);
        s += __shfl_xor(s, 4); s += __shfl_xor(s, 8);
        ss[m][g] = s;
      }
    float mx = 0.f;
    #pragma unroll
    for (int m=0;m<4;m++)
      #pragma unroll
      for (int g=0;g<4;g++) mx = fmaxf(mx, ss[m][g]);
    mx = fmaxf(mx, __shfl_xor(mx, 16));
    mx = fmaxf(mx, __shfl_xor(mx, 32));
    if (lane == 0){
      const int rowbase = bm + wr*64;
      const int b_ = rowbase >> 11, qc_ = (rowbase >> 6) & 31;
      const int h_ = (colbase >> 6) & 7;
      float* M = which ? Mk : Mq;
      M[(b_*8 + h_)*32 + qc_] = sqrtf(mx) * 1.01f;
    }
  }
}

// ---------------- windowed flash attention, 4-wave pipelined (S^T formulation) ----------------
__global__ __launch_bounds__(256,2) void attn_kernel(
    const unsigned short* __restrict__ Q,
    const unsigned short* __restrict__ K,
    const unsigned short* __restrict__ VT,
    const float* __restrict__ alib,
    const float* __restrict__ Mqa,
    const float* __restrict__ Mka,
    unsigned short* __restrict__ Y){
  __shared__ unsigned short Ks[2][64*64];
  __shared__ unsigned short Vs[2][64*64];
  __shared__ unsigned short Ps[4][16][72];
  __shared__ float MkS[32];
  __shared__ float wred[4];
  __shared__ int lst[32];
  __shared__ int nsh;
  const int tid = threadIdx.x, wid = tid >> 6, lane = tid & 63;
  const int fr = lane & 15, fq = lane >> 4;
  const int fr7 = fr & 7;
  const int id = blockIdx.x;
  const int h = id >> 7, r_ = id & 127, b = r_ >> 5, qc = r_ & 31;
  const int bh = b*8 + h;
  const int q0 = qc*64 + wid*16;
  const unsigned short* Qp = Q  + (size_t)bh * 131072;
  const unsigned short* Kp = K  + (size_t)bh * 131072;
  const unsigned short* Vp = VT + (size_t)bh * 131072;
  const float nmh2 = alib[(size_t)h * 4194304 + 1] * LOG2E;
  const float MqMk0 = Mqa[bh*32 + qc];
  if (tid < 32) MkS[tid] = Mka[bh*32 + tid];

  // per-wave 16 q rows; lane fr = q row, fq = kv quad group
  bf16x8 qf[2];
  #pragma unroll
  for (int kk=0;kk<2;kk++)
    qf[kk] = *(const bf16x8*)(Qp + (size_t)(q0 + fr)*64 + kk*32 + fq*8);

  f32x4 o[4];
  #pragma unroll
  for (int ni=0;ni<4;ni++) o[ni] = (f32x4){0.f,0.f,0.f,0.f};
  float mr = -1e30f, lr = 0.f;
  const float qi = (float)(q0 + fr);
  const float qb = nmh2 * qi;
  f32x4 ka[4];
  #pragma unroll
  for (int ni=0;ni<4;ni++)
    #pragma unroll
    for (int g=0;g<4;g++) ka[ni][g] = nmh2 * (float)(ni*16 + fq*4 + g);

  auto stage = [&](int kt, int buf){
    const int kb = kt * 64;
    #pragma unroll
    for (int it=0; it<2; it++){
      const int s = it*256 + tid;
      const int row = s >> 3, c = s & 7;
      const int sc = c ^ (row & 7);
      gload16(Kp + (size_t)(kb + row)*64 + sc*8, (void*)(Ks[buf] + (it*256 + wid*64)*8));
      gload16(Vp + (size_t)row*2048 + kb + sc*8, (void*)(Vs[buf] + (it*256 + wid*64)*8));
    }
  };

  auto compute = [&](int kt, int buf, bool diag){
    const int kb = kt * 64;
    const unsigned short* KsB = Ks[buf];
    const unsigned short* VsB = Vs[buf];
    bf16x8 kf[4][2], vf[4][2];
    #pragma unroll
    for (int ni=0;ni<4;ni++)
      #pragma unroll
      for (int kk=0;kk<2;kk++){
        const int r = ni*16 + fr;
        const int sw = ((kk*4 + fq) ^ fr7) * 8;
        kf[ni][kk] = *(const bf16x8*)&KsB[r*64 + sw];
        vf[ni][kk] = *(const bf16x8*)&VsB[r*64 + sw];
      }

    // S^T: lane holds col q = q0+fr, rows kv = kb + ni*16 + fq*4 + g
    f32x4 st[4];
    const f32x4 fz = {0.f,0.f,0.f,0.f};
    #pragma unroll
    for (int ni=0;ni<4;ni++){
      f32x4 t0 = __builtin_amdgcn_mfma_f32_16x16x32_bf16(kf[ni][0], qf[0], fz, 0,0,0);
      st[ni] = __builtin_amdgcn_mfma_f32_16x16x32_bf16(kf[ni][1], qf[1], t0, 0,0,0);
    }

    // ALiBi bias: separable off-diagonal, abs on diagonal
    float cadd;
    if (diag){
      const float base = qi - (float)(kb + fq*4);
      #pragma unroll
      for (int ni=0;ni<4;ni++)
        #pragma unroll
        for (int g=0;g<4;g++){
          const float d = fabsf(base - (float)(ni*16 + g));
          st[ni][g] = fmaf(nmh2, d, st[ni][g]);
        }
      cadd = 0.f;
    } else {
      const float s1 = (kt > qc) ? 1.f : -1.f;
      #pragma unroll
      for (int ni=0;ni<4;ni++)
        #pragma unroll
        for (int g=0;g<4;g++)
          st[ni][g] = fmaf(s1, ka[ni][g], st[ni][g]);
      cadd = s1 * (nmh2 * (float)kb - qb);
    }

    float m0 = fmaxf(fmaxf(st[0][0], st[0][1]), fmaxf(st[0][2], st[0][3]));
    float m1 = fmaxf(fmaxf(st[1][0], st[1][1]), fmaxf(st[1][2], st[1][3]));
    float m2 = fmaxf(fmaxf(st[2][0], st[2][1]), fmaxf(st[2][2], st[2][3]));
    float m3 = fmaxf(fmaxf(st[3][0], st[3][1]), fmaxf(st[3][2], st[3][3]));
    float tm = fmaxf(fmaxf(m0, m1), fmaxf(m2, m3));
    tm = fmaxf(tm, __shfl_xor(tm, 16));
    tm = fmaxf(tm, __shfl_xor(tm, 32));
    const float tmt = tm + cadd;

    const bool nog = __all(tmt <= mr);
    float mn, sc;
    if (nog){
      mn = mr;
    } else {
      mn = fmaxf(mr, tmt);
      sc = exp2f(mr - mn);
      mr = mn;
    }
    const float mexp = mn - cadd;
    float rs = 0.f;
    #pragma unroll
    for (int ni=0;ni<4;ni++){
      #pragma unroll
      for (int g=0;g<4;g++){
        const float p = exp2f(st[ni][g] - mexp);
        st[ni][g] = p;
        rs += p;
      }
    }
    rs += __shfl_xor(rs, 16);
    rs += __shfl_xor(rs, 32);
    if (nog){
      lr += rs;
    } else {
      lr = lr*sc + rs;
      #pragma unroll
      for (int g=0;g<4;g++){
        const float sv = __shfl(sc, fq*4 + g);
        #pragma unroll
        for (int ni=0;ni<4;ni++) o[ni][g] *= sv;
      }
    }
    #pragma unroll
    for (int ni=0;ni<4;ni++){
      uint2 pk;
      pk.x = cvtpk(st[ni][0], st[ni][1]);
      pk.y = cvtpk(st[ni][2], st[ni][3]);
      *(uint2*)&Ps[wid][fr][ni*16 + fq*4] = pk;
    }

    bf16x8 pf[2];
    #pragma unroll
    for (int kk=0;kk<2;kk++)
      pf[kk] = *(const bf16x8*)&Ps[wid][fr][kk*32 + fq*8];
    #pragma unroll
    for (int ni=0;ni<4;ni++){
      o[ni] = __builtin_amdgcn_mfma_f32_16x16x32_bf16(pf[0], vf[ni][0], o[ni], 0,0,0);
      o[ni] = __builtin_amdgcn_mfma_f32_16x16x32_bf16(pf[1], vf[ni][1], o[ni], 0,0,0);
    }
  };

  // ---- diagonal tile (serial) ----
  stage(qc, 0);
  asm volatile("s_waitcnt vmcnt(0)" ::: "memory");
  __builtin_amdgcn_sched_barrier(0);
  __builtin_amdgcn_s_barrier();
  compute(qc, 0, true);

  // ---- threshold ----
  {
    float m = mr;
    #pragma unroll
    for (int d=1; d<16; d<<=1) m = fminf(m, __shfl_xor(m, d));
    if (lane == 0) wred[wid] = m;
  }
  __syncthreads();
  const float thresh = fminf(fminf(wred[0], wred[1]), fminf(wred[2], wred[3])) - 16.0f;

  // ---- build tile list (block-uniform) ----
  if (tid == 0){
    float maxMk = 0.f;
    #pragma unroll
    for (int t=0; t<32; t++) maxMk = fmaxf(maxMk, MkS[t]);
    int n = 0;
    for (int dt = 1; dt < 32; dt++){
      const float biasmax = nmh2 * (float)((dt - 1)*64 + 1);
      if (MqMk0 * maxMk + biasmax < thresh) break;
      int kt = qc + dt;
      if (kt < 32 && MqMk0 * MkS[kt] + biasmax >= thresh) lst[n++] = kt;
      kt = qc - dt;
      if (kt >= 0 && MqMk0 * MkS[kt] + biasmax >= thresh) lst[n++] = kt;
    }
    nsh = n;
  }
  __syncthreads();
  const int n = nsh;

  // ---- pipelined loop: tile j lives in buffer (j+1)&1 ----
  if (n > 0){
    stage(lst[0], 1);
    for (int j = 0; j < n; j++){
      asm volatile("s_waitcnt lgkmcnt(0)" ::: "memory");
      __builtin_amdgcn_sched_barrier(0);
      __builtin_amdgcn_s_barrier();            // safe to overwrite buf j&1
      if (j + 1 < n){
        stage(lst[j+1], j & 1);
        asm volatile("s_waitcnt vmcnt(4)" ::: "memory");
      } else {
        asm volatile("s_waitcnt vmcnt(0)" ::: "memory");
      }
      __builtin_amdgcn_sched_barrier(0);
      __builtin_amdgcn_s_barrier();            // buf (j+1)&1 staged for all waves
      compute(lst[j], (j+1)&1, false);
    }
  }

  // ---- epilogue ----
  {
    const float inv = 1.0f / lr;
    #pragma unroll
    for (int g=0;g<4;g++){
      const float iv = __shfl(inv, fq*4 + g);
      const int t = q0 + fq*4 + g;
      #pragma unroll
      for (int ni=0;ni<4;ni++)
        Y[(size_t)(b*2048 + t)*512 + h*64 + ni*16 + fr] = f2b(o[ni][g] * iv);
    }
  }
}

// ---------------- output projection GEMM (BK=64, global_load_lds) ----------------
__global__ __launch_bounds__(256,2) void gemm_proj_kernel(
    const unsigned short* __restrict__ A,
    const unsigned short* __restrict__ Bt,
    const float* __restrict__ bias,
    float* __restrict__ out){
  __shared__ unsigned short As[128*64];
  __shared__ unsigned short Bs[128*64];
  const int tid = threadIdx.x, wid = tid >> 6, lane = tid & 63;
  const int wr = wid >> 1, wc = wid & 1;
  const int fr = lane & 15, fq = lane >> 4;
  const int fr7 = fr & 7;
  const int bm = blockIdx.x * 128, bn = blockIdx.y * 128;
  f32x4 acc[4][4];
  #pragma unroll
  for (int m=0;m<4;m++)
    #pragma unroll
    for (int n=0;n<4;n++) acc[m][n] = (f32x4){0.f,0.f,0.f,0.f};

  for (int k0 = 0; k0 < 512; k0 += 64){
    __syncthreads();
    #pragma unroll
    for (int it=0; it<4; it++){
      const int s = it*256 + tid;
      const int row = s >> 3, c = s & 7;
      const int sc = c ^ (row & 7);
      void* al = (void*)(As + (it*256 + wid*64)*8);
      void* bl = (void*)(Bs + (it*256 + wid*64)*8);
      gload16(A  + (size_t)(bm + row)*512 + k0 + sc*8, al);
      gload16(Bt + (size_t)(bn + row)*512 + k0 + sc*8, bl);
    }
    __syncthreads();
    bf16x8 af[4][2], bfv[4][2];
    #pragma unroll
    for (int m=0;m<4;m++)
      #pragma unroll
      for (int kk=0;kk<2;kk++)
        af[m][kk]  = *(const bf16x8*)&As[(wr*64 + m*16 + fr)*64 + (((kk*4+fq)^fr7)*8)];
    #pragma unroll
    for (int n=0;n<4;n++)
      #pragma unroll
      for (int kk=0;kk<2;kk++)
        bfv[n][kk] = *(const bf16x8*)&Bs[(wc*64 + n*16 + fr)*64 + (((kk*4+fq)^fr7)*8)];
    #pragma unroll
    for (int kk=0;kk<2;kk++)
      #pragma unroll
      for (int m=0;m<4;m++)
        #pragma unroll
        for (int n=0;n<4;n++)
          acc[m][n] = __builtin_amdgcn_mfma_f32_16x16x32_bf16(af[m][kk], bfv[n][kk], acc[m][n], 0,0,0);
  }

  #pragma unroll
  for (int m=0;m<4;m++){
    const int row0 = bm + wr*64 + m*16 + fq*4;
    #pragma unroll
    for (int n=0;n<4;n++){
      const int col = bn + wc*64 + n*16 + fr;
      const float bv = bias[col];
      #pragma unroll
      for (int g=0; g<4; g++)
        out[(size_t)(row0 + g)*512 + col] = acc[m][n][g] + bv;
    }
  }
}

// ---------------- launch ----------------
extern "C" void kernel_launch(void* const* d_in, const int* in_sizes, int n_in,
                              void* d_out, int out_size, void* d_ws, size_t ws_size,
                              hipStream_t stream){
  const float* x     = (const float*)d_in[0];
  const float* Wqkv  = (const float*)d_in[1];
  const float* bqkv  = (const float*)d_in[2];
  const float* Wproj = (const float*)d_in[3];
  const float* bproj = (const float*)d_in[4];
  const float* alib  = (const float*)d_in[5];
  char* ws = (char*)d_ws;
  unsigned short* xb     = (unsigned short*)(ws);
  unsigned short* wqkvT  = (unsigned short*)(ws + 8388608);
  unsigned short* wprojT = (unsigned short*)(ws + 9961472);
  unsigned short* Qb     = (unsigned short*)(ws + 10485760);
  unsigned short* Kb     = (unsigned short*)(ws + 18874368);
  unsigned short* VTb    = (unsigned short*)(ws + 27262976);
  unsigned short* Yb     = (unsigned short*)(ws + 35651584);
  float* out = (float*)d_out;
  float* Mq = out + 4194304 - 2048;
  float* Mk = Mq + 1024;

  prep_kernel<<<2304, 256, 0, stream>>>(x, Wqkv, Wproj, xb, wqkvT, wprojT);
  gemm_qkv_kernel<<<dim3(64, 12), 256, 0, stream>>>(xb, wqkvT, bqkv, Qb, Kb, VTb, Mq, Mk);
  attn_kernel<<<1024, 256, 0, stream>>>(Qb, Kb, VTb, alib, Mq, Mk, Yb);
  gemm_proj_kernel<<<dim3(64, 4), 256, 0, stream>>>(Yb, wprojT, bproj, out);
}

// Round 7
// 68.980 us; speedup vs baseline: 3.0020x; 1.0278x over previous
//
#include <hip/hip_runtime.h>
#include <hip/hip_bf16.h>

#define LOG2E 1.4426950408889634f

typedef __attribute__((ext_vector_type(8))) short short8;
typedef __attribute__((ext_vector_type(8))) __bf16 bf16x8;
typedef __attribute__((ext_vector_type(4))) float f32x4;

__device__ __forceinline__ unsigned short f2b(float f){
  unsigned int u = __builtin_bit_cast(unsigned int, f);
  u += 0x7fffu + ((u >> 16) & 1u);
  return (unsigned short)(u >> 16);
}

__device__ __forceinline__ unsigned int cvtpk(float lo, float hi){
  unsigned int r;
  asm("v_cvt_pk_bf16_f32 %0, %1, %2" : "=v"(r) : "v"(lo), "v"(hi));
  return r;
}

__device__ __forceinline__ void gload16(const void* g, void* l){
  __builtin_amdgcn_global_load_lds(
      (const __attribute__((address_space(1))) unsigned int*)g,
      (__attribute__((address_space(3))) unsigned int*)l, 16, 0, 0);
}

// ---------------- merged prep kernel: x->bf16, Wqkv^T, Wproj^T ----------------
__global__ __launch_bounds__(256) void prep_kernel(
    const float* __restrict__ x, const float* __restrict__ Wqkv, const float* __restrict__ Wproj,
    unsigned short* __restrict__ xb, unsigned short* __restrict__ wqkvT, unsigned short* __restrict__ wprojT){
  __shared__ unsigned short T[64][72];
  const int bid = blockIdx.x, tid = threadIdx.x;
  if (bid < 2048){
    size_t i = ((size_t)bid * 256 + tid) * 8;
    float4 a = *(const float4*)(x + i);
    float4 b = *(const float4*)(x + i + 4);
    short8 s;
    s[0]=(short)f2b(a.x); s[1]=(short)f2b(a.y); s[2]=(short)f2b(a.z); s[3]=(short)f2b(a.w);
    s[4]=(short)f2b(b.x); s[5]=(short)f2b(b.y); s[6]=(short)f2b(b.z); s[7]=(short)f2b(b.w);
    *(short8*)(xb + i) = s;
    return;
  }
  const float* in; unsigned short* out; int R, C, bx, by;
  if (bid < 2240){ int t = bid - 2048; bx = t % 24; by = t / 24; in = Wqkv; out = wqkvT; R = 512; C = 1536; }
  else           { int t = bid - 2240; bx = t % 8;  by = t / 8;  in = Wproj; out = wprojT; R = 512; C = 512; }
  const int r0 = by * 64, c0 = bx * 64;
  {
    const int i = tid >> 2, jg = (tid & 3) * 16;
    const float* src = in + (size_t)(r0 + i) * C + c0 + jg;
    #pragma unroll
    for (int e = 0; e < 16; e += 4){
      float4 v = *(const float4*)(src + e);
      T[i][jg + e + 0] = f2b(v.x);
      T[i][jg + e + 1] = f2b(v.y);
      T[i][jg + e + 2] = f2b(v.z);
      T[i][jg + e + 3] = f2b(v.w);
    }
  }
  __syncthreads();
  {
    const int j = tid >> 2, ig = (tid & 3) * 16;
    short8 w0, w1;
    #pragma unroll
    for (int e = 0; e < 8; e++) w0[e] = (short)T[ig + e][j];
    #pragma unroll
    for (int e = 0; e < 8; e++) w1[e] = (short)T[ig + 8 + e][j];
    unsigned short* dst = out + (size_t)(c0 + j) * R + r0 + ig;
    *(short8*)dst = w0;
    *(short8*)(dst + 8) = w1;
  }
}

// ---------------- QKV GEMM (BK=64, global_load_lds) + fused norm epilogue ----------------
__global__ __launch_bounds__(256,2) void gemm_qkv_kernel(
    const unsigned short* __restrict__ A,
    const unsigned short* __restrict__ Bt,
    const float* __restrict__ bias,
    unsigned short* __restrict__ Qb,
    unsigned short* __restrict__ Kb,
    unsigned short* __restrict__ VTb,
    float* __restrict__ Mq, float* __restrict__ Mk){
  __shared__ unsigned short As[128*64];
  __shared__ unsigned short Bs[128*64];
  const int tid = threadIdx.x, wid = tid >> 6, lane = tid & 63;
  const int wr = wid >> 1, wc = wid & 1;
  const int fr = lane & 15, fq = lane >> 4;
  const int fr7 = fr & 7;
  const int bm = blockIdx.x * 128, bn = blockIdx.y * 128;
  f32x4 acc[4][4];
  #pragma unroll
  for (int m=0;m<4;m++)
    #pragma unroll
    for (int n=0;n<4;n++) acc[m][n] = (f32x4){0.f,0.f,0.f,0.f};

  for (int k0 = 0; k0 < 512; k0 += 64){
    __syncthreads();
    #pragma unroll
    for (int it=0; it<4; it++){
      const int s = it*256 + tid;
      const int row = s >> 3, c = s & 7;
      const int sc = c ^ (row & 7);
      void* al = (void*)(As + (it*256 + wid*64)*8);
      void* bl = (void*)(Bs + (it*256 + wid*64)*8);
      gload16(A  + (size_t)(bm + row)*512 + k0 + sc*8, al);
      gload16(Bt + (size_t)(bn + row)*512 + k0 + sc*8, bl);
    }
    __syncthreads();
    bf16x8 af[4][2], bfv[4][2];
    #pragma unroll
    for (int m=0;m<4;m++)
      #pragma unroll
      for (int kk=0;kk<2;kk++)
        af[m][kk]  = *(const bf16x8*)&As[(wr*64 + m*16 + fr)*64 + (((kk*4+fq)^fr7)*8)];
    #pragma unroll
    for (int n=0;n<4;n++)
      #pragma unroll
      for (int kk=0;kk<2;kk++)
        bfv[n][kk] = *(const bf16x8*)&Bs[(wc*64 + n*16 + fr)*64 + (((kk*4+fq)^fr7)*8)];
    #pragma unroll
    for (int kk=0;kk<2;kk++)
      #pragma unroll
      for (int m=0;m<4;m++)
        #pragma unroll
        for (int n=0;n<4;n++)
          acc[m][n] = __builtin_amdgcn_mfma_f32_16x16x32_bf16(af[m][kk], bfv[n][kk], acc[m][n], 0,0,0);
  }

  const float SCQ = 0.125f * LOG2E;
  const int colbase = bn + wc*64;
  const int which = colbase >> 9;
  float ss[4][4];
  #pragma unroll
  for (int m=0;m<4;m++)
    #pragma unroll
    for (int g=0;g<4;g++) ss[m][g] = 0.f;

  #pragma unroll
  for (int m=0;m<4;m++){
    const int row0 = bm + wr*64 + m*16 + fq*4;
    const int b_ = row0 >> 11, t_ = row0 & 2047;
    #pragma unroll
    for (int n=0;n<4;n++){
      const int col = colbase + n*16 + fr;
      const int c = col & 511, hh = c >> 6, dd = c & 63;
      const float bv = bias[col];
      if (which == 0){
        #pragma unroll
        for (int g=0; g<4; g++){
          const float v = (acc[m][n][g] + bv) * SCQ;
          ss[m][g] = fmaf(v, v, ss[m][g]);
          Qb[((size_t)(b_*8 + hh)*2048 + t_ + g)*64 + dd] = f2b(v);
        }
      } else if (which == 1){
        #pragma unroll
        for (int g=0; g<4; g++){
          const float v = acc[m][n][g] + bv;
          ss[m][g] = fmaf(v, v, ss[m][g]);
          Kb[((size_t)(b_*8 + hh)*2048 + t_ + g)*64 + dd] = f2b(v);
        }
      } else {
        uint2 pk;
        pk.x = cvtpk(acc[m][n][0] + bv, acc[m][n][1] + bv);
        pk.y = cvtpk(acc[m][n][2] + bv, acc[m][n][3] + bv);
        *(uint2*)&VTb[((size_t)(b_*8 + hh)*64 + dd)*2048 + t_] = pk;
      }
    }
  }

  if (which <= 1){
    #pragma unroll
    for (int m=0;m<4;m++)
      #pragma unroll
      for (int g=0;g<4;g++){
        float s = ss[m][g];
        s += __shfl_xor(s, 1); s += __shfl_xor(s, 2);
        s += __shfl_xor(s, 4); s += __shfl_xor(s, 8);
        ss[m][g] = s;
      }
    float mx = 0.f;
    #pragma unroll
    for (int m=0;m<4;m++)
      #pragma unroll
      for (int g=0;g<4;g++) mx = fmaxf(mx, ss[m][g]);
    mx = fmaxf(mx, __shfl_xor(mx, 16));
    mx = fmaxf(mx, __shfl_xor(mx, 32));
    if (lane == 0){
      const int rowbase = bm + wr*64;
      const int b_ = rowbase >> 11, qc_ = (rowbase >> 6) & 31;
      const int h_ = (colbase >> 6) & 7;
      float* M = which ? Mk : Mq;
      M[(b_*8 + h_)*32 + qc_] = sqrtf(mx) * 1.01f;
    }
  }
}

// ---------------- windowed flash attention, 4-wave pipelined (S^T formulation) ----------------
__global__ __launch_bounds__(256,3) void attn_kernel(
    const unsigned short* __restrict__ Q,
    const unsigned short* __restrict__ K,
    const unsigned short* __restrict__ VT,
    const float* __restrict__ alib,
    const float* __restrict__ Mqa,
    const float* __restrict__ Mka,
    unsigned short* __restrict__ Y){
  __shared__ unsigned short Ks[2][64*64];
  __shared__ unsigned short Vs[2][64*64];
  __shared__ unsigned short Ps[4][16][72];
  __shared__ float MkS[32];
  __shared__ float wred[4];
  __shared__ int lst[32];
  __shared__ int nsh;
  const int tid = threadIdx.x, wid = tid >> 6, lane = tid & 63;
  const int fr = lane & 15, fq = lane >> 4;
  const int fr7 = fr & 7;
  const int id = blockIdx.x;
  const int h = id >> 7, r_ = id & 127, b = r_ >> 5, qc = r_ & 31;
  const int bh = b*8 + h;
  const int q0 = qc*64 + wid*16;
  const unsigned short* Qp = Q  + (size_t)bh * 131072;
  const unsigned short* Kp = K  + (size_t)bh * 131072;
  const unsigned short* Vp = VT + (size_t)bh * 131072;
  const float nmh2 = alib[(size_t)h * 4194304 + 1] * LOG2E;
  const float MqMk0 = Mqa[bh*32 + qc];
  if (tid < 32) MkS[tid] = Mka[bh*32 + tid];

  // per-wave 16 q rows; lane fr = q row, fq = kv quad group
  bf16x8 qf[2];
  #pragma unroll
  for (int kk=0;kk<2;kk++)
    qf[kk] = *(const bf16x8*)(Qp + (size_t)(q0 + fr)*64 + kk*32 + fq*8);

  // ones B-fragment for the row-sum MFMA (bf16 1.0 = 0x3F80)
  bf16x8 ones;
  #pragma unroll
  for (int e=0;e<8;e++) ones[e] = __builtin_bit_cast(__bf16, (unsigned short)0x3F80);

  f32x4 o[4], osum;
  #pragma unroll
  for (int ni=0;ni<4;ni++) o[ni] = (f32x4){0.f,0.f,0.f,0.f};
  osum = (f32x4){0.f,0.f,0.f,0.f};
  float mr = -1e30f;
  const float qi = (float)(q0 + fr);
  const float qb = nmh2 * qi;
  f32x4 ka[4];
  #pragma unroll
  for (int ni=0;ni<4;ni++)
    #pragma unroll
    for (int g=0;g<4;g++) ka[ni][g] = nmh2 * (float)(ni*16 + fq*4 + g);

  auto stage = [&](int kt, int buf){
    const int kb = kt * 64;
    #pragma unroll
    for (int it=0; it<2; it++){
      const int s = it*256 + tid;
      const int row = s >> 3, c = s & 7;
      const int sc = c ^ (row & 7);
      gload16(Kp + (size_t)(kb + row)*64 + sc*8, (void*)(Ks[buf] + (it*256 + wid*64)*8));
      gload16(Vp + (size_t)row*2048 + kb + sc*8, (void*)(Vs[buf] + (it*256 + wid*64)*8));
    }
  };

  auto compute = [&](int kt, int buf, bool diag){
    const int kb = kt * 64;
    const unsigned short* KsB = Ks[buf];
    const unsigned short* VsB = Vs[buf];
    bf16x8 kf[4][2], vf[4][2];
    #pragma unroll
    for (int ni=0;ni<4;ni++)
      #pragma unroll
      for (int kk=0;kk<2;kk++){
        const int r = ni*16 + fr;
        const int sw = ((kk*4 + fq) ^ fr7) * 8;
        kf[ni][kk] = *(const bf16x8*)&KsB[r*64 + sw];
        vf[ni][kk] = *(const bf16x8*)&VsB[r*64 + sw];
      }

    // S^T: lane holds col q = q0+fr, rows kv = kb + ni*16 + fq*4 + g
    f32x4 st[4];
    const f32x4 fz = {0.f,0.f,0.f,0.f};
    #pragma unroll
    for (int ni=0;ni<4;ni++){
      f32x4 t0 = __builtin_amdgcn_mfma_f32_16x16x32_bf16(kf[ni][0], qf[0], fz, 0,0,0);
      st[ni] = __builtin_amdgcn_mfma_f32_16x16x32_bf16(kf[ni][1], qf[1], t0, 0,0,0);
    }

    // ALiBi bias: separable off-diagonal, abs on diagonal
    float cadd;
    if (diag){
      const float base = qi - (float)(kb + fq*4);
      #pragma unroll
      for (int ni=0;ni<4;ni++)
        #pragma unroll
        for (int g=0;g<4;g++){
          const float d = fabsf(base - (float)(ni*16 + g));
          st[ni][g] = fmaf(nmh2, d, st[ni][g]);
        }
      cadd = 0.f;
    } else {
      const float s1 = (kt > qc) ? 1.f : -1.f;
      #pragma unroll
      for (int ni=0;ni<4;ni++)
        #pragma unroll
        for (int g=0;g<4;g++)
          st[ni][g] = fmaf(s1, ka[ni][g], st[ni][g]);
      cadd = s1 * (nmh2 * (float)kb - qb);
    }

    float m0 = fmaxf(fmaxf(st[0][0], st[0][1]), fmaxf(st[0][2], st[0][3]));
    float m1 = fmaxf(fmaxf(st[1][0], st[1][1]), fmaxf(st[1][2], st[1][3]));
    float m2 = fmaxf(fmaxf(st[2][0], st[2][1]), fmaxf(st[2][2], st[2][3]));
    float m3 = fmaxf(fmaxf(st[3][0], st[3][1]), fmaxf(st[3][2], st[3][3]));
    float tm = fmaxf(fmaxf(m0, m1), fmaxf(m2, m3));
    tm = fmaxf(tm, __shfl_xor(tm, 16));
    tm = fmaxf(tm, __shfl_xor(tm, 32));
    const float tmt = tm + cadd;

    const bool nog = __all(tmt <= mr);
    float mn = mr, sc;
    if (!nog){
      mn = fmaxf(mr, tmt);
      sc = exp2f(mr - mn);
      mr = mn;
    }
    const float mexp = mn - cadd;
    #pragma unroll
    for (int ni=0;ni<4;ni++)
      #pragma unroll
      for (int g=0;g<4;g++)
        st[ni][g] = exp2f(st[ni][g] - mexp);

    if (!nog){
      #pragma unroll
      for (int g=0;g<4;g++){
        const float sv = __shfl(sc, fq*4 + g);
        #pragma unroll
        for (int ni=0;ni<4;ni++) o[ni][g] *= sv;
        osum[g] *= sv;
      }
    }
    #pragma unroll
    for (int ni=0;ni<4;ni++){
      uint2 pk;
      pk.x = cvtpk(st[ni][0], st[ni][1]);
      pk.y = cvtpk(st[ni][2], st[ni][3]);
      *(uint2*)&Ps[wid][fr][ni*16 + fq*4] = pk;
    }

    bf16x8 pf[2];
    #pragma unroll
    for (int kk=0;kk<2;kk++)
      pf[kk] = *(const bf16x8*)&Ps[wid][fr][kk*32 + fq*8];
    #pragma unroll
    for (int ni=0;ni<4;ni++){
      o[ni] = __builtin_amdgcn_mfma_f32_16x16x32_bf16(pf[0], vf[ni][0], o[ni], 0,0,0);
      o[ni] = __builtin_amdgcn_mfma_f32_16x16x32_bf16(pf[1], vf[ni][1], o[ni], 0,0,0);
    }
    osum = __builtin_amdgcn_mfma_f32_16x16x32_bf16(pf[0], ones, osum, 0,0,0);
    osum = __builtin_amdgcn_mfma_f32_16x16x32_bf16(pf[1], ones, osum, 0,0,0);
  };

  // ---- diagonal tile (serial) ----
  stage(qc, 0);
  asm volatile("s_waitcnt vmcnt(0)" ::: "memory");
  __builtin_amdgcn_sched_barrier(0);
  __builtin_amdgcn_s_barrier();
  compute(qc, 0, true);

  // ---- thresholds (block + per-wave) ----
  float wm = mr;
  #pragma unroll
  for (int d=1; d<16; d<<=1) wm = fminf(wm, __shfl_xor(wm, d));
  if (lane == 0) wred[wid] = wm;
  __syncthreads();
  const float thresh  = fminf(fminf(wred[0], wred[1]), fminf(wred[2], wred[3])) - 14.0f;
  const float threshW = wm - 14.0f;

  // ---- build tile list (block-uniform) ----
  if (tid == 0){
    float maxMk = 0.f;
    #pragma unroll
    for (int t=0; t<32; t++) maxMk = fmaxf(maxMk, MkS[t]);
    int n = 0;
    for (int dt = 1; dt < 32; dt++){
      const float biasmax = nmh2 * (float)((dt - 1)*64 + 1);
      if (MqMk0 * maxMk + biasmax < thresh) break;
      int kt = qc + dt;
      if (kt < 32 && MqMk0 * MkS[kt] + biasmax >= thresh) lst[n++] = kt;
      kt = qc - dt;
      if (kt >= 0 && MqMk0 * MkS[kt] + biasmax >= thresh) lst[n++] = kt;
    }
    nsh = n;
  }
  __syncthreads();
  const int n = nsh;

  // ---- pipelined loop: tile j lives in buffer (j+1)&1 ----
  if (n > 0){
    stage(lst[0], 1);
    for (int j = 0; j < n; j++){
      asm volatile("s_waitcnt lgkmcnt(0)" ::: "memory");
      __builtin_amdgcn_sched_barrier(0);
      __builtin_amdgcn_s_barrier();            // safe to overwrite buf j&1
      if (j + 1 < n){
        stage(lst[j+1], j & 1);
        asm volatile("s_waitcnt vmcnt(4)" ::: "memory");
      } else {
        asm volatile("s_waitcnt vmcnt(0)" ::: "memory");
      }
      __builtin_amdgcn_sched_barrier(0);
      __builtin_amdgcn_s_barrier();            // buf (j+1)&1 staged for all waves
      const int kt = lst[j];
      // per-wave refined skip: exact distance from this wave's 16 q-rows
      const int dminW = (kt > qc) ? (kt*64 - (q0 + 15)) : (q0 - (kt*64 + 63));
      if (MqMk0 * MkS[kt] + nmh2 * (float)dminW >= threshW)
        compute(kt, (j+1)&1, false);
    }
  }

  // ---- epilogue: osum holds per-row denominators in o-layout ----
  #pragma unroll
  for (int g=0;g<4;g++){
    const float iv = 1.0f / osum[g];
    const int t = q0 + fq*4 + g;
    #pragma unroll
    for (int ni=0;ni<4;ni++)
      Y[(size_t)(b*2048 + t)*512 + h*64 + ni*16 + fr] = f2b(o[ni][g] * iv);
  }
}

// ---------------- output projection GEMM (BK=64, global_load_lds) ----------------
__global__ __launch_bounds__(256,2) void gemm_proj_kernel(
    const unsigned short* __restrict__ A,
    const unsigned short* __restrict__ Bt,
    const float* __restrict__ bias,
    float* __restrict__ out){
  __shared__ unsigned short As[128*64];
  __shared__ unsigned short Bs[128*64];
  const int tid = threadIdx.x, wid = tid >> 6, lane = tid & 63;
  const int wr = wid >> 1, wc = wid & 1;
  const int fr = lane & 15, fq = lane >> 4;
  const int fr7 = fr & 7;
  const int bm = blockIdx.x * 128, bn = blockIdx.y * 128;
  f32x4 acc[4][4];
  #pragma unroll
  for (int m=0;m<4;m++)
    #pragma unroll
    for (int n=0;n<4;n++) acc[m][n] = (f32x4){0.f,0.f,0.f,0.f};

  for (int k0 = 0; k0 < 512; k0 += 64){
    __syncthreads();
    #pragma unroll
    for (int it=0; it<4; it++){
      const int s = it*256 + tid;
      const int row = s >> 3, c = s & 7;
      const int sc = c ^ (row & 7);
      void* al = (void*)(As + (it*256 + wid*64)*8);
      void* bl = (void*)(Bs + (it*256 + wid*64)*8);
      gload16(A  + (size_t)(bm + row)*512 + k0 + sc*8, al);
      gload16(Bt + (size_t)(bn + row)*512 + k0 + sc*8, bl);
    }
    __syncthreads();
    bf16x8 af[4][2], bfv[4][2];
    #pragma unroll
    for (int m=0;m<4;m++)
      #pragma unroll
      for (int kk=0;kk<2;kk++)
        af[m][kk]  = *(const bf16x8*)&As[(wr*64 + m*16 + fr)*64 + (((kk*4+fq)^fr7)*8)];
    #pragma unroll
    for (int n=0;n<4;n++)
      #pragma unroll
      for (int kk=0;kk<2;kk++)
        bfv[n][kk] = *(const bf16x8*)&Bs[(wc*64 + n*16 + fr)*64 + (((kk*4+fq)^fr7)*8)];
    #pragma unroll
    for (int kk=0;kk<2;kk++)
      #pragma unroll
      for (int m=0;m<4;m++)
        #pragma unroll
        for (int n=0;n<4;n++)
          acc[m][n] = __builtin_amdgcn_mfma_f32_16x16x32_bf16(af[m][kk], bfv[n][kk], acc[m][n], 0,0,0);
  }

  #pragma unroll
  for (int m=0;m<4;m++){
    const int row0 = bm + wr*64 + m*16 + fq*4;
    #pragma unroll
    for (int n=0;n<4;n++){
      const int col = bn + wc*64 + n*16 + fr;
      const float bv = bias[col];
      #pragma unroll
      for (int g=0; g<4; g++)
        out[(size_t)(row0 + g)*512 + col] = acc[m][n][g] + bv;
    }
  }
}

// ---------------- launch ----------------
extern "C" void kernel_launch(void* const* d_in, const int* in_sizes, int n_in,
                              void* d_out, int out_size, void* d_ws, size_t ws_size,
                              hipStream_t stream){
  const float* x     = (const float*)d_in[0];
  const float* Wqkv  = (const float*)d_in[1];
  const float* bqkv  = (const float*)d_in[2];
  const float* Wproj = (const float*)d_in[3];
  const float* bproj = (const float*)d_in[4];
  const float* alib  = (const float*)d_in[5];
  char* ws = (char*)d_ws;
  unsigned short* xb     = (unsigned short*)(ws);
  unsigned short* wqkvT  = (unsigned short*)(ws + 8388608);
  unsigned short* wprojT = (unsigned short*)(ws + 9961472);
  unsigned short* Qb     = (unsigned short*)(ws + 10485760);
  unsigned short* Kb     = (unsigned short*)(ws + 18874368);
  unsigned short* VTb    = (unsigned short*)(ws + 27262976);
  unsigned short* Yb     = (unsigned short*)(ws + 35651584);
  float* out = (float*)d_out;
  float* Mq = out + 4194304 - 2048;
  float* Mk = Mq + 1024;

  prep_kernel<<<2304, 256, 0, stream>>>(x, Wqkv, Wproj, xb, wqkvT, wprojT);
  gemm_qkv_kernel<<<dim3(64, 12), 256, 0, stream>>>(xb, wqkvT, bqkv, Qb, Kb, VTb, Mq, Mk);
  attn_kernel<<<1024, 256, 0, stream>>>(Qb, Kb, VTb, alib, Mq, Mk, Yb);
  gemm_proj_kernel<<<dim3(64, 4), 256, 0, stream>>>(Yb, wprojT, bproj, out);
}

// Round 8
// 66.529 us; speedup vs baseline: 3.1126x; 1.0368x over previous
//
#include <hip/hip_runtime.h>
#include <hip/hip_bf16.h>

#define LOG2E 1.4426950408889634f

typedef __attribute__((ext_vector_type(8))) short short8;
typedef __attribute__((ext_vector_type(8))) __bf16 bf16x8;
typedef __attribute__((ext_vector_type(4))) float f32x4;

__device__ __forceinline__ unsigned short f2b(float f){
  unsigned int u = __builtin_bit_cast(unsigned int, f);
  u += 0x7fffu + ((u >> 16) & 1u);
  return (unsigned short)(u >> 16);
}

__device__ __forceinline__ unsigned int cvtpk(float lo, float hi){
  unsigned int r;
  asm("v_cvt_pk_bf16_f32 %0, %1, %2" : "=v"(r) : "v"(lo), "v"(hi));
  return r;
}

__device__ __forceinline__ void gload16(const void* g, void* l){
  __builtin_amdgcn_global_load_lds(
      (const __attribute__((address_space(1))) unsigned int*)g,
      (__attribute__((address_space(3))) unsigned int*)l, 16, 0, 0);
}

// ---------------- merged prep kernel: x->bf16, Wqkv^T, Wproj^T ----------------
__global__ __launch_bounds__(256) void prep_kernel(
    const float* __restrict__ x, const float* __restrict__ Wqkv, const float* __restrict__ Wproj,
    unsigned short* __restrict__ xb, unsigned short* __restrict__ wqkvT, unsigned short* __restrict__ wprojT){
  __shared__ unsigned short T[64][72];
  const int bid = blockIdx.x, tid = threadIdx.x;
  if (bid < 2048){
    size_t i = ((size_t)bid * 256 + tid) * 8;
    float4 a = *(const float4*)(x + i);
    float4 b = *(const float4*)(x + i + 4);
    short8 s;
    s[0]=(short)f2b(a.x); s[1]=(short)f2b(a.y); s[2]=(short)f2b(a.z); s[3]=(short)f2b(a.w);
    s[4]=(short)f2b(b.x); s[5]=(short)f2b(b.y); s[6]=(short)f2b(b.z); s[7]=(short)f2b(b.w);
    *(short8*)(xb + i) = s;
    return;
  }
  const float* in; unsigned short* out; int R, C, bx, by;
  if (bid < 2240){ int t = bid - 2048; bx = t % 24; by = t / 24; in = Wqkv; out = wqkvT; R = 512; C = 1536; }
  else           { int t = bid - 2240; bx = t % 8;  by = t / 8;  in = Wproj; out = wprojT; R = 512; C = 512; }
  const int r0 = by * 64, c0 = bx * 64;
  {
    const int i = tid >> 2, jg = (tid & 3) * 16;
    const float* src = in + (size_t)(r0 + i) * C + c0 + jg;
    #pragma unroll
    for (int e = 0; e < 16; e += 4){
      float4 v = *(const float4*)(src + e);
      T[i][jg + e + 0] = f2b(v.x);
      T[i][jg + e + 1] = f2b(v.y);
      T[i][jg + e + 2] = f2b(v.z);
      T[i][jg + e + 3] = f2b(v.w);
    }
  }
  __syncthreads();
  {
    const int j = tid >> 2, ig = (tid & 3) * 16;
    short8 w0, w1;
    #pragma unroll
    for (int e = 0; e < 8; e++) w0[e] = (short)T[ig + e][j];
    #pragma unroll
    for (int e = 0; e < 8; e++) w1[e] = (short)T[ig + 8 + e][j];
    unsigned short* dst = out + (size_t)(c0 + j) * R + r0 + ig;
    *(short8*)dst = w0;
    *(short8*)(dst + 8) = w1;
  }
}

// ---------------- QKV GEMM (BK=64, global_load_lds, XCD-swizzled) + norm epilogue ----------------
__global__ __launch_bounds__(256,2) void gemm_qkv_kernel(
    const unsigned short* __restrict__ A,
    const unsigned short* __restrict__ Bt,
    const float* __restrict__ bias,
    unsigned short* __restrict__ Qb,
    unsigned short* __restrict__ Kb,
    unsigned short* __restrict__ VTb,
    float* __restrict__ Mq, float* __restrict__ Mk){
  __shared__ unsigned short As[128*64];
  __shared__ unsigned short Bs[128*64];
  const int tid = threadIdx.x, wid = tid >> 6, lane = tid & 63;
  const int wr = wid >> 1, wc = wid & 1;
  const int fr = lane & 15, fq = lane >> 4;
  const int fr7 = fr & 7;
  // XCD swizzle: same-bm blocks colocate on one XCD (A-tile + full B fit 4MB L2)
  const int orig = blockIdx.x;
  const int xcd = orig & 7, idx = orig >> 3;
  const int bm = (xcd + 8*(idx/12)) * 128;
  const int bn = (idx % 12) * 128;
  f32x4 acc[4][4];
  #pragma unroll
  for (int m=0;m<4;m++)
    #pragma unroll
    for (int n=0;n<4;n++) acc[m][n] = (f32x4){0.f,0.f,0.f,0.f};

  for (int k0 = 0; k0 < 512; k0 += 64){
    __syncthreads();
    #pragma unroll
    for (int it=0; it<4; it++){
      const int s = it*256 + tid;
      const int row = s >> 3, c = s & 7;
      const int sc = c ^ (row & 7);
      void* al = (void*)(As + (it*256 + wid*64)*8);
      void* bl = (void*)(Bs + (it*256 + wid*64)*8);
      gload16(A  + (size_t)(bm + row)*512 + k0 + sc*8, al);
      gload16(Bt + (size_t)(bn + row)*512 + k0 + sc*8, bl);
    }
    __syncthreads();
    bf16x8 af[4][2], bfv[4][2];
    #pragma unroll
    for (int m=0;m<4;m++)
      #pragma unroll
      for (int kk=0;kk<2;kk++)
        af[m][kk]  = *(const bf16x8*)&As[(wr*64 + m*16 + fr)*64 + (((kk*4+fq)^fr7)*8)];
    #pragma unroll
    for (int n=0;n<4;n++)
      #pragma unroll
      for (int kk=0;kk<2;kk++)
        bfv[n][kk] = *(const bf16x8*)&Bs[(wc*64 + n*16 + fr)*64 + (((kk*4+fq)^fr7)*8)];
    #pragma unroll
    for (int kk=0;kk<2;kk++)
      #pragma unroll
      for (int m=0;m<4;m++)
        #pragma unroll
        for (int n=0;n<4;n++)
          acc[m][n] = __builtin_amdgcn_mfma_f32_16x16x32_bf16(af[m][kk], bfv[n][kk], acc[m][n], 0,0,0);
  }

  const float SCQ = 0.125f * LOG2E;
  const int colbase = bn + wc*64;
  const int which = colbase >> 9;
  float ss[4][4];
  #pragma unroll
  for (int m=0;m<4;m++)
    #pragma unroll
    for (int g=0;g<4;g++) ss[m][g] = 0.f;

  #pragma unroll
  for (int m=0;m<4;m++){
    const int row0 = bm + wr*64 + m*16 + fq*4;
    const int b_ = row0 >> 11, t_ = row0 & 2047;
    #pragma unroll
    for (int n=0;n<4;n++){
      const int col = colbase + n*16 + fr;
      const int c = col & 511, hh = c >> 6, dd = c & 63;
      const float bv = bias[col];
      if (which == 0){
        #pragma unroll
        for (int g=0; g<4; g++){
          const float v = (acc[m][n][g] + bv) * SCQ;
          ss[m][g] = fmaf(v, v, ss[m][g]);
          Qb[((size_t)(b_*8 + hh)*2048 + t_ + g)*64 + dd] = f2b(v);
        }
      } else if (which == 1){
        #pragma unroll
        for (int g=0; g<4; g++){
          const float v = acc[m][n][g] + bv;
          ss[m][g] = fmaf(v, v, ss[m][g]);
          Kb[((size_t)(b_*8 + hh)*2048 + t_ + g)*64 + dd] = f2b(v);
        }
      } else {
        uint2 pk;
        pk.x = cvtpk(acc[m][n][0] + bv, acc[m][n][1] + bv);
        pk.y = cvtpk(acc[m][n][2] + bv, acc[m][n][3] + bv);
        *(uint2*)&VTb[((size_t)(b_*8 + hh)*64 + dd)*2048 + t_] = pk;
      }
    }
  }

  if (which <= 1){
    #pragma unroll
    for (int m=0;m<4;m++)
      #pragma unroll
      for (int g=0;g<4;g++){
        float s = ss[m][g];
        s += __shfl_xor(s, 1); s += __shfl_xor(s, 2);
        s += __shfl_xor(s, 4); s += __shfl_xor(s, 8);
        ss[m][g] = s;
      }
    float mx = 0.f;
    #pragma unroll
    for (int m=0;m<4;m++)
      #pragma unroll
      for (int g=0;g<4;g++) mx = fmaxf(mx, ss[m][g]);
    mx = fmaxf(mx, __shfl_xor(mx, 16));
    mx = fmaxf(mx, __shfl_xor(mx, 32));
    if (lane == 0){
      const int rowbase = bm + wr*64;
      const int b_ = rowbase >> 11, qc_ = (rowbase >> 6) & 31;
      const int h_ = (colbase >> 6) & 7;
      float* M = which ? Mk : Mq;
      M[(b_*8 + h_)*32 + qc_] = sqrtf(mx) * 1.01f;
    }
  }
}

// ---------------- windowed flash attention, 4-wave pipelined (S^T formulation) ----------------
__global__ __launch_bounds__(256,3) void attn_kernel(
    const unsigned short* __restrict__ Q,
    const unsigned short* __restrict__ K,
    const unsigned short* __restrict__ VT,
    const float* __restrict__ alib,
    const float* __restrict__ Mqa,
    const float* __restrict__ Mka,
    unsigned short* __restrict__ Y){
  __shared__ unsigned short Ks[2][64*64];
  __shared__ unsigned short Vs[2][64*64];
  __shared__ unsigned short Ps[4][16][72];
  __shared__ float MkS[32];
  __shared__ float wred[4];
  __shared__ int lst[32];
  __shared__ int nsh;
  const int tid = threadIdx.x, wid = tid >> 6, lane = tid & 63;
  const int fr = lane & 15, fq = lane >> 4;
  const int fr7 = fr & 7;
  // XCD swizzle within each h-group: qc-quads of same (b,h) colocate per XCD
  // (overlapping KV windows -> L2 hits); h order preserved for LPT.
  const int id = blockIdx.x;
  const int h = id >> 7;
  const int low3 = id & 7, idx4 = (id & 127) >> 3;   // idx4 in 0..15
  const int b = idx4 >> 2, off = idx4 & 3;
  const int quad = (low3 - b) & 7;
  const int qc = quad*4 + off;
  const int bh = b*8 + h;
  const int q0 = qc*64 + wid*16;
  const unsigned short* Qp = Q  + (size_t)bh * 131072;
  const unsigned short* Kp = K  + (size_t)bh * 131072;
  const unsigned short* Vp = VT + (size_t)bh * 131072;
  const float nmh2 = alib[(size_t)h * 4194304 + 1] * LOG2E;
  const float MqMk0 = Mqa[bh*32 + qc];
  if (tid < 32) MkS[tid] = Mka[bh*32 + tid];

  // per-wave 16 q rows; lane fr = q row, fq = kv quad group
  bf16x8 qf[2];
  #pragma unroll
  for (int kk=0;kk<2;kk++)
    qf[kk] = *(const bf16x8*)(Qp + (size_t)(q0 + fr)*64 + kk*32 + fq*8);

  // ones B-fragment for the row-sum MFMA (bf16 1.0 = 0x3F80)
  bf16x8 ones;
  #pragma unroll
  for (int e=0;e<8;e++) ones[e] = __builtin_bit_cast(__bf16, (unsigned short)0x3F80);

  f32x4 o[4], osum;
  #pragma unroll
  for (int ni=0;ni<4;ni++) o[ni] = (f32x4){0.f,0.f,0.f,0.f};
  osum = (f32x4){0.f,0.f,0.f,0.f};
  float mr = -1e30f;
  const float qi = (float)(q0 + fr);
  const float qb = nmh2 * qi;
  f32x4 ka[4];
  #pragma unroll
  for (int ni=0;ni<4;ni++)
    #pragma unroll
    for (int g=0;g<4;g++) ka[ni][g] = nmh2 * (float)(ni*16 + fq*4 + g);

  auto stage = [&](int kt, int buf){
    const int kb = kt * 64;
    #pragma unroll
    for (int it=0; it<2; it++){
      const int s = it*256 + tid;
      const int row = s >> 3, c = s & 7;
      const int sc = c ^ (row & 7);
      gload16(Kp + (size_t)(kb + row)*64 + sc*8, (void*)(Ks[buf] + (it*256 + wid*64)*8));
      gload16(Vp + (size_t)row*2048 + kb + sc*8, (void*)(Vs[buf] + (it*256 + wid*64)*8));
    }
  };

  auto compute = [&](int kt, int buf, bool diag){
    const int kb = kt * 64;
    const unsigned short* KsB = Ks[buf];
    const unsigned short* VsB = Vs[buf];
    bf16x8 kf[4][2], vf[4][2];
    #pragma unroll
    for (int ni=0;ni<4;ni++)
      #pragma unroll
      for (int kk=0;kk<2;kk++){
        const int r = ni*16 + fr;
        const int sw = ((kk*4 + fq) ^ fr7) * 8;
        kf[ni][kk] = *(const bf16x8*)&KsB[r*64 + sw];
        vf[ni][kk] = *(const bf16x8*)&VsB[r*64 + sw];
      }

    // S^T: lane holds col q = q0+fr, rows kv = kb + ni*16 + fq*4 + g
    f32x4 st[4];
    const f32x4 fz = {0.f,0.f,0.f,0.f};
    #pragma unroll
    for (int ni=0;ni<4;ni++){
      f32x4 t0 = __builtin_amdgcn_mfma_f32_16x16x32_bf16(kf[ni][0], qf[0], fz, 0,0,0);
      st[ni] = __builtin_amdgcn_mfma_f32_16x16x32_bf16(kf[ni][1], qf[1], t0, 0,0,0);
    }

    // ALiBi bias: separable off-diagonal, abs on diagonal
    float cadd;
    if (diag){
      const float base = qi - (float)(kb + fq*4);
      #pragma unroll
      for (int ni=0;ni<4;ni++)
        #pragma unroll
        for (int g=0;g<4;g++){
          const float d = fabsf(base - (float)(ni*16 + g));
          st[ni][g] = fmaf(nmh2, d, st[ni][g]);
        }
      cadd = 0.f;
    } else {
      const float s1 = (kt > qc) ? 1.f : -1.f;
      #pragma unroll
      for (int ni=0;ni<4;ni++)
        #pragma unroll
        for (int g=0;g<4;g++)
          st[ni][g] = fmaf(s1, ka[ni][g], st[ni][g]);
      cadd = s1 * (nmh2 * (float)kb - qb);
    }

    float m0 = fmaxf(fmaxf(st[0][0], st[0][1]), fmaxf(st[0][2], st[0][3]));
    float m1 = fmaxf(fmaxf(st[1][0], st[1][1]), fmaxf(st[1][2], st[1][3]));
    float m2 = fmaxf(fmaxf(st[2][0], st[2][1]), fmaxf(st[2][2], st[2][3]));
    float m3 = fmaxf(fmaxf(st[3][0], st[3][1]), fmaxf(st[3][2], st[3][3]));
    float tm = fmaxf(fmaxf(m0, m1), fmaxf(m2, m3));
    tm = fmaxf(tm, __shfl_xor(tm, 16));
    tm = fmaxf(tm, __shfl_xor(tm, 32));
    const float tmt = tm + cadd;

    const bool nog = __all(tmt <= mr);
    float mn = mr, sc;
    if (!nog){
      mn = fmaxf(mr, tmt);
      sc = exp2f(mr - mn);
      mr = mn;
    }
    const float mexp = mn - cadd;
    #pragma unroll
    for (int ni=0;ni<4;ni++)
      #pragma unroll
      for (int g=0;g<4;g++)
        st[ni][g] = exp2f(st[ni][g] - mexp);

    if (!nog){
      #pragma unroll
      for (int g=0;g<4;g++){
        const float sv = __shfl(sc, fq*4 + g);
        #pragma unroll
        for (int ni=0;ni<4;ni++) o[ni][g] *= sv;
        osum[g] *= sv;
      }
    }
    #pragma unroll
    for (int ni=0;ni<4;ni++){
      uint2 pk;
      pk.x = cvtpk(st[ni][0], st[ni][1]);
      pk.y = cvtpk(st[ni][2], st[ni][3]);
      *(uint2*)&Ps[wid][fr][ni*16 + fq*4] = pk;
    }

    bf16x8 pf[2];
    #pragma unroll
    for (int kk=0;kk<2;kk++)
      pf[kk] = *(const bf16x8*)&Ps[wid][fr][kk*32 + fq*8];
    #pragma unroll
    for (int ni=0;ni<4;ni++){
      o[ni] = __builtin_amdgcn_mfma_f32_16x16x32_bf16(pf[0], vf[ni][0], o[ni], 0,0,0);
      o[ni] = __builtin_amdgcn_mfma_f32_16x16x32_bf16(pf[1], vf[ni][1], o[ni], 0,0,0);
    }
    osum = __builtin_amdgcn_mfma_f32_16x16x32_bf16(pf[0], ones, osum, 0,0,0);
    osum = __builtin_amdgcn_mfma_f32_16x16x32_bf16(pf[1], ones, osum, 0,0,0);
  };

  // ---- prologue: stage diag + first ring tile together, overlap ----
  const int e0 = (qc + 1 < 32) ? qc + 1 : qc - 1;               // always exists
  const int e1 = (qc + 1 < 32 && qc - 1 >= 0) ? qc - 1 : -1;
  stage(qc, 0);
  stage(e0, 1);
  asm volatile("s_waitcnt vmcnt(4)" ::: "memory");   // drain only diag's 4 loads
  __builtin_amdgcn_sched_barrier(0);
  __builtin_amdgcn_s_barrier();
  compute(qc, 0, true);

  // ---- thresholds (block + per-wave) ----
  float wm = mr;
  #pragma unroll
  for (int d=1; d<16; d<<=1) wm = fminf(wm, __shfl_xor(wm, d));
  if (lane == 0) wred[wid] = wm;
  __syncthreads();
  const float thresh  = fminf(fminf(wred[0], wred[1]), fminf(wred[2], wred[3])) - 14.0f;
  const float threshW = wm - 14.0f;

  // ---- build tile list: e1 first (ring-1 always processed), then dt>=2 ----
  if (tid == 0){
    float maxMk = 0.f;
    #pragma unroll
    for (int t=0; t<32; t++) maxMk = fmaxf(maxMk, MkS[t]);
    int n = 0;
    if (e1 >= 0) lst[n++] = e1;
    for (int dt = 2; dt < 32; dt++){
      const float biasmax = nmh2 * (float)((dt - 1)*64 + 1);
      if (MqMk0 * maxMk + biasmax < thresh) break;
      int kt = qc + dt;
      if (kt < 32 && MqMk0 * MkS[kt] + biasmax >= thresh) lst[n++] = kt;
      kt = qc - dt;
      if (kt >= 0 && MqMk0 * MkS[kt] + biasmax >= thresh) lst[n++] = kt;
    }
    nsh = n;
  }
  __syncthreads();
  const int nt = nsh + 1;            // tiles: e0, lst[0..nsh-1]; e0 already in buf1

  // ---- pipelined loop: tile j lives in buffer (j+1)&1 ----
  for (int j = 0; j < nt; j++){
    const int kt = (j == 0) ? e0 : lst[j-1];
    asm volatile("s_waitcnt lgkmcnt(0)" ::: "memory");
    __builtin_amdgcn_sched_barrier(0);
    __builtin_amdgcn_s_barrier();            // safe to overwrite buf j&1
    if (j + 1 < nt){
      stage((j == 0) ? lst[0] : lst[j], j & 1);
      asm volatile("s_waitcnt vmcnt(4)" ::: "memory");
    } else {
      asm volatile("s_waitcnt vmcnt(0)" ::: "memory");
    }
    __builtin_amdgcn_sched_barrier(0);
    __builtin_amdgcn_s_barrier();            // buf (j+1)&1 staged for all waves
    // per-wave refined skip: exact distance from this wave's 16 q-rows
    const int dminW = (kt > qc) ? (kt*64 - (q0 + 15)) : (q0 - (kt*64 + 63));
    if (MqMk0 * MkS[kt] + nmh2 * (float)dminW >= threshW)
      compute(kt, (j+1)&1, false);
  }

  // ---- epilogue: osum holds per-row denominators in o-layout ----
  #pragma unroll
  for (int g=0;g<4;g++){
    const float iv = 1.0f / osum[g];
    const int t = q0 + fq*4 + g;
    #pragma unroll
    for (int ni=0;ni<4;ni++)
      Y[(size_t)(b*2048 + t)*512 + h*64 + ni*16 + fr] = f2b(o[ni][g] * iv);
  }
}

// ---------------- output projection GEMM (BK=64, global_load_lds, XCD-swizzled) ----------------
__global__ __launch_bounds__(256,2) void gemm_proj_kernel(
    const unsigned short* __restrict__ A,
    const unsigned short* __restrict__ Bt,
    const float* __restrict__ bias,
    float* __restrict__ out){
  __shared__ unsigned short As[128*64];
  __shared__ unsigned short Bs[128*64];
  const int tid = threadIdx.x, wid = tid >> 6, lane = tid & 63;
  const int wr = wid >> 1, wc = wid & 1;
  const int fr = lane & 15, fq = lane >> 4;
  const int fr7 = fr & 7;
  const int orig = blockIdx.x;
  const int xcd = orig & 7, idx = orig >> 3;
  const int bm = (xcd + 8*(idx >> 2)) * 128;
  const int bn = (idx & 3) * 128;
  f32x4 acc[4][4];
  #pragma unroll
  for (int m=0;m<4;m++)
    #pragma unroll
    for (int n=0;n<4;n++) acc[m][n] = (f32x4){0.f,0.f,0.f,0.f};

  for (int k0 = 0; k0 < 512; k0 += 64){
    __syncthreads();
    #pragma unroll
    for (int it=0; it<4; it++){
      const int s = it*256 + tid;
      const int row = s >> 3, c = s & 7;
      const int sc = c ^ (row & 7);
      void* al = (void*)(As + (it*256 + wid*64)*8);
      void* bl = (void*)(Bs + (it*256 + wid*64)*8);
      gload16(A  + (size_t)(bm + row)*512 + k0 + sc*8, al);
      gload16(Bt + (size_t)(bn + row)*512 + k0 + sc*8, bl);
    }
    __syncthreads();
    bf16x8 af[4][2], bfv[4][2];
    #pragma unroll
    for (int m=0;m<4;m++)
      #pragma unroll
      for (int kk=0;kk<2;kk++)
        af[m][kk]  = *(const bf16x8*)&As[(wr*64 + m*16 + fr)*64 + (((kk*4+fq)^fr7)*8)];
    #pragma unroll
    for (int n=0;n<4;n++)
      #pragma unroll
      for (int kk=0;kk<2;kk++)
        bfv[n][kk] = *(const bf16x8*)&Bs[(wc*64 + n*16 + fr)*64 + (((kk*4+fq)^fr7)*8)];
    #pragma unroll
    for (int kk=0;kk<2;kk++)
      #pragma unroll
      for (int m=0;m<4;m++)
        #pragma unroll
        for (int n=0;n<4;n++)
          acc[m][n] = __builtin_amdgcn_mfma_f32_16x16x32_bf16(af[m][kk], bfv[n][kk], acc[m][n], 0,0,0);
  }

  #pragma unroll
  for (int m=0;m<4;m++){
    const int row0 = bm + wr*64 + m*16 + fq*4;
    #pragma unroll
    for (int n=0;n<4;n++){
      const int col = bn + wc*64 + n*16 + fr;
      const float bv = bias[col];
      #pragma unroll
      for (int g=0; g<4; g++)
        out[(size_t)(row0 + g)*512 + col] = acc[m][n][g] + bv;
    }
  }
}

// ---------------- launch ----------------
extern "C" void kernel_launch(void* const* d_in, const int* in_sizes, int n_in,
                              void* d_out, int out_size, void* d_ws, size_t ws_size,
                              hipStream_t stream){
  const float* x     = (const float*)d_in[0];
  const float* Wqkv  = (const float*)d_in[1];
  const float* bqkv  = (const float*)d_in[2];
  const float* Wproj = (const float*)d_in[3];
  const float* bproj = (const float*)d_in[4];
  const float* alib  = (const float*)d_in[5];
  char* ws = (char*)d_ws;
  unsigned short* xb     = (unsigned short*)(ws);
  unsigned short* wqkvT  = (unsigned short*)(ws + 8388608);
  unsigned short* wprojT = (unsigned short*)(ws + 9961472);
  unsigned short* Qb     = (unsigned short*)(ws + 10485760);
  unsigned short* Kb     = (unsigned short*)(ws + 18874368);
  unsigned short* VTb    = (unsigned short*)(ws + 27262976);
  unsigned short* Yb     = (unsigned short*)(ws + 35651584);
  float* out = (float*)d_out;
  float* Mq = out + 4194304 - 2048;
  float* Mk = Mq + 1024;

  prep_kernel<<<2304, 256, 0, stream>>>(x, Wqkv, Wproj, xb, wqkvT, wprojT);
  gemm_qkv_kernel<<<768, 256, 0, stream>>>(xb, wqkvT, bqkv, Qb, Kb, VTb, Mq, Mk);
  attn_kernel<<<1024, 256, 0, stream>>>(Qb, Kb, VTb, alib, Mq, Mk, Yb);
  gemm_proj_kernel<<<256, 256, 0, stream>>>(Yb, wprojT, bproj, out);
}